// Round 3
// baseline (7816.479 us; speedup 1.0000x reference)
//
#include <hip/hip_runtime.h>
#include <hip/hip_bf16.h>

#define N_NODES 131072
#define NGRAPH  256
#define NMAXN   512
#define NEDGE   1048576
#define FIN     128
#define HDIM    64
#define K1Q     128

// ---------------------------------------------------------------- utilities
__global__ void k_zero_f(float* __restrict__ p, int n) {
    int i = blockIdx.x * blockDim.x + threadIdx.x;
    if (i < n) p[i] = 0.f;
}
__global__ void k_zero_i(int* __restrict__ p, int n) {
    int i = blockIdx.x * blockDim.x + threadIdx.x;
    if (i < n) p[i] = 0;
}

// degree = (# in-edges) ; dinv = rsqrt(deg+1)
__global__ void k_deg_acc(const int* __restrict__ dst, float* __restrict__ deg) {
    int e = blockIdx.x * blockDim.x + threadIdx.x;
    if (e < NEDGE) atomicAdd(&deg[dst[e]], 1.0f);
}
__global__ void k_dinv(float* __restrict__ d) {
    int i = blockIdx.x * blockDim.x + threadIdx.x;
    if (i < N_NODES) d[i] = rsqrtf(d[i] + 1.0f);
}

// ------------------------------------------------- edge sort by graph (dst>>9)
__global__ void k_hist(const int* __restrict__ dst, int* __restrict__ cnt) {
    __shared__ int h[NGRAPH];
    for (int i = threadIdx.x; i < NGRAPH; i += blockDim.x) h[i] = 0;
    __syncthreads();
    int base = blockIdx.x * blockDim.x * 4;
    for (int j = 0; j < 4; ++j) {
        int e = base + j * blockDim.x + threadIdx.x;
        if (e < NEDGE) atomicAdd(&h[dst[e] >> 9], 1);
    }
    __syncthreads();
    for (int i = threadIdx.x; i < NGRAPH; i += blockDim.x) atomicAdd(&cnt[i], h[i]);
}
__global__ void k_scan(const int* __restrict__ cnt, int* __restrict__ starts,
                       int* __restrict__ cursor) {
    if (threadIdx.x == 0) {
        int s = 0;
        for (int g = 0; g < NGRAPH; ++g) { starts[g] = s; cursor[g] = s; s += cnt[g]; }
        starts[NGRAPH] = s;
    }
}
__global__ void k_scatter(const int* __restrict__ src, const int* __restrict__ dst,
                          int* __restrict__ cursor, int* __restrict__ ssrc,
                          int* __restrict__ sdst) {
    int e = blockIdx.x * blockDim.x + threadIdx.x;
    if (e < NEDGE) {
        int d = dst[e];
        int p = atomicAdd(&cursor[d >> 9], 1);
        ssrc[p] = src[e];
        sdst[p] = d;
    }
}

// ------------------------------------------------------------- generic GEMM
// out[M,CO] = A[M,K] @ W[K,CO] (+bias) (+relu). A strided by lda, out by ldo.
// MODE: 0 = plain, 1 = +bias, 2 = +bias+relu
template<int TM, int K, int CO, int MODE>
__global__ __launch_bounds__(256) void k_gemm(
    const float* __restrict__ A, int lda,
    const float* __restrict__ W, const float* __restrict__ bias,
    float* __restrict__ out, int ldo, int M)
{
    constexpr int WTS = K + 4;
    __shared__ float As[TM * K];
    __shared__ float Wt[CO * WTS];
    const int tid = threadIdx.x;
    const int row0 = blockIdx.x * TM;

    for (int i = tid; i < K * CO; i += 256) {
        int k = i / CO, c = i - k * CO;
        Wt[c * WTS + k] = W[i];
    }
    constexpr int VR = K / 4;
    for (int i = tid; i < TM * VR; i += 256) {
        int r = i / VR, v = i - r * VR;
        int gr = row0 + r;
        float4 val = make_float4(0.f, 0.f, 0.f, 0.f);
        if (gr < M) val = *(const float4*)(A + (size_t)gr * lda + v * 4);
        *(float4*)(As + r * K + v * 4) = val;
    }
    __syncthreads();

    constexpr int G = 256 / CO;
    constexpr int RPT = TM / G;
    const int co = tid % CO;
    const int g = tid / CO;

    float4 wr[K / 4];
#pragma unroll
    for (int kk = 0; kk < K / 4; ++kk) wr[kk] = *(const float4*)(Wt + co * WTS + kk * 4);

    float acc[RPT];
#pragma unroll
    for (int r = 0; r < RPT; ++r) acc[r] = 0.f;

    for (int kk = 0; kk < K / 4; ++kk) {
        float4 w = wr[kk];
#pragma unroll
        for (int r = 0; r < RPT; ++r) {
            float4 a = *(const float4*)(As + (g * RPT + r) * K + kk * 4);
            acc[r] += a.x * w.x + a.y * w.y + a.z * w.z + a.w * w.w;
        }
    }
    float b = 0.f;
    if (MODE >= 1) b = bias[co];
#pragma unroll
    for (int r = 0; r < RPT; ++r) {
        int gr = row0 + g * RPT + r;
        if (gr < M) {
            float v = acc[r] + b;
            if (MODE == 2) v = fmaxf(v, 0.f);
            out[(size_t)gr * ldo + co] = v;
        }
    }
}

// --------------------------------------- GCN aggregation (per-graph, LDS atomics)
// out[n] = bias + T[n]*dinv[n]^2 + sum_{e: dst=n} T[src]*dinv[src]*dinv[dst]
// Processes 32 columns; pointers T/bias/out pre-offset by the column offset.
template<int RELU>
__global__ __launch_bounds__(256) void k_gcn_agg(
    const float* __restrict__ T, int ldt,
    const float* __restrict__ dinv, const float* __restrict__ bias,
    const int* __restrict__ ssrc, const int* __restrict__ sdst,
    const int* __restrict__ starts,
    float* __restrict__ out, int ldo)
{
    constexpr int LS = 36;                 // padded row stride (banks)
    __shared__ float Tl[NMAXN * LS];
    __shared__ float Ac[NMAXN * LS];
    __shared__ float dl[NMAXN];
    const int g = blockIdx.x;
    const int tid = threadIdx.x;
    const int node0 = g * NMAXN;

    for (int i = tid; i < NMAXN; i += 256) dl[i] = dinv[node0 + i];
    __syncthreads();
    for (int i = tid; i < NMAXN * 8; i += 256) {
        int r = i >> 3, c4 = (i & 7) << 2;
        float4 v = *(const float4*)(T + (size_t)(node0 + r) * ldt + c4);
        *(float4*)(Tl + r * LS + c4) = v;
        float w = dl[r] * dl[r];
        float4 b4 = *(const float4*)(bias + c4);
        float4 a;
        a.x = v.x * w + b4.x; a.y = v.y * w + b4.y;
        a.z = v.z * w + b4.z; a.w = v.w * w + b4.w;
        *(float4*)(Ac + r * LS + c4) = a;
    }
    __syncthreads();
    const int e0 = starts[g], e1 = starts[g + 1];
    const int nit = (e1 - e0) << 3;
    for (int i = tid; i < nit; i += 256) {
        int e = e0 + (i >> 3), c4 = (i & 7) << 2;
        int ls = ssrc[e] & (NMAXN - 1), ld = sdst[e] & (NMAXN - 1);
        float w = dl[ls] * dl[ld];
        float4 v = *(const float4*)(Tl + ls * LS + c4);
        float* ap = Ac + ld * LS + c4;
        atomicAdd(ap + 0, v.x * w); atomicAdd(ap + 1, v.y * w);
        atomicAdd(ap + 2, v.z * w); atomicAdd(ap + 3, v.w * w);
    }
    __syncthreads();
    for (int i = tid; i < NMAXN * 8; i += 256) {
        int r = i >> 3, c4 = (i & 7) << 2;
        float4 a = *(const float4*)(Ac + r * LS + c4);
        if (RELU) {
            a.x = fmaxf(a.x, 0.f); a.y = fmaxf(a.y, 0.f);
            a.z = fmaxf(a.z, 0.f); a.w = fmaxf(a.w, 0.f);
        }
        *(float4*)(out + (size_t)(node0 + r) * ldo + c4) = a;
    }
}

// ------------------------------------------------------ attention (flash-style)
// grid = NGRAPH*4 blocks (graph, head); block = 128 threads = one query each.
// Writes O[g, q, h*16+d] = softmax(QK^T/8) V   (no residual here)
template<int NK, bool QSH>
__global__ __launch_bounds__(128) void k_attn(
    const float* __restrict__ Q, const float* __restrict__ K,
    const float* __restrict__ V, float* __restrict__ O)
{
    __shared__ float Ks[NK * 16];
    __shared__ float Vs[NK * 16];
    const int g = blockIdx.x >> 2;
    const int h = blockIdx.x & 3;
    const int tid = threadIdx.x;
    for (int i = tid; i < NK * 4; i += 128) {
        int k = i >> 2, dc = (i & 3) << 2;
        const size_t off = ((size_t)g * NK + k) * HDIM + h * 16 + dc;
        *(float4*)(Ks + k * 16 + dc) = *(const float4*)(K + off);
        *(float4*)(Vs + k * 16 + dc) = *(const float4*)(V + off);
    }
    __syncthreads();
    const int q = tid;
    const float* qp = QSH ? (Q + (size_t)q * HDIM + h * 16)
                          : (Q + ((size_t)g * K1Q + q) * HDIM + h * 16);
    float qv[16];
#pragma unroll
    for (int d = 0; d < 16; ++d) qv[d] = qp[d];

    float m0 = -1e30f, l0 = 0.f, m1 = -1e30f, l1 = 0.f;
    float acc0[16], acc1[16];
#pragma unroll
    for (int d = 0; d < 16; ++d) { acc0[d] = 0.f; acc1[d] = 0.f; }

    for (int k = 0; k < NK; k += 2) {
        float s0 = 0.f, s1 = 0.f;
#pragma unroll
        for (int d4 = 0; d4 < 4; ++d4) {
            float4 ka = *(const float4*)(Ks + k * 16 + d4 * 4);
            float4 kb = *(const float4*)(Ks + (k + 1) * 16 + d4 * 4);
            s0 += qv[d4*4] * ka.x + qv[d4*4+1] * ka.y + qv[d4*4+2] * ka.z + qv[d4*4+3] * ka.w;
            s1 += qv[d4*4] * kb.x + qv[d4*4+1] * kb.y + qv[d4*4+2] * kb.z + qv[d4*4+3] * kb.w;
        }
        s0 *= 0.125f; s1 *= 0.125f;
        float mn0 = fmaxf(m0, s0);
        float cr0 = __expf(m0 - mn0), p0 = __expf(s0 - mn0);
        l0 = l0 * cr0 + p0; m0 = mn0;
        float mn1 = fmaxf(m1, s1);
        float cr1 = __expf(m1 - mn1), p1 = __expf(s1 - mn1);
        l1 = l1 * cr1 + p1; m1 = mn1;
#pragma unroll
        for (int d4 = 0; d4 < 4; ++d4) {
            float4 va = *(const float4*)(Vs + k * 16 + d4 * 4);
            float4 vb = *(const float4*)(Vs + (k + 1) * 16 + d4 * 4);
            acc0[d4*4]   = acc0[d4*4]   * cr0 + p0 * va.x;
            acc0[d4*4+1] = acc0[d4*4+1] * cr0 + p0 * va.y;
            acc0[d4*4+2] = acc0[d4*4+2] * cr0 + p0 * va.z;
            acc0[d4*4+3] = acc0[d4*4+3] * cr0 + p0 * va.w;
            acc1[d4*4]   = acc1[d4*4]   * cr1 + p1 * vb.x;
            acc1[d4*4+1] = acc1[d4*4+1] * cr1 + p1 * vb.y;
            acc1[d4*4+2] = acc1[d4*4+2] * cr1 + p1 * vb.z;
            acc1[d4*4+3] = acc1[d4*4+3] * cr1 + p1 * vb.w;
        }
    }
    float mn = fmaxf(m0, m1);
    float c0 = __expf(m0 - mn), c1 = __expf(m1 - mn);
    float inv = 1.f / (l0 * c0 + l1 * c1);
    float* op = O + ((size_t)g * K1Q + q) * HDIM + h * 16;
#pragma unroll
    for (int d = 0; d < 16; ++d) op[d] = (acc0[d] * c0 + acc1[d] * c1) * inv;
}

// PMA2: 1 query, 128 keys. block = 256 = 4 graphs x 64 lanes (lane = h*16+d)
__global__ __launch_bounds__(256) void k_attn_pma2(
    const float* __restrict__ Q2p, const float* __restrict__ K3,
    const float* __restrict__ V3, float* __restrict__ O3)
{
    const int t = threadIdx.x;
    const int lane = t & 63;
    const int g = blockIdx.x * 4 + (t >> 6);
    const float q = Q2p[lane];
    const float* Kg = K3 + (size_t)g * 128 * HDIM + lane;
    const float* Vg = V3 + (size_t)g * 128 * HDIM + lane;
    float m = -1e30f, l = 0.f, acc = 0.f;
    for (int k = 0; k < 128; ++k) {
        float s = q * Kg[(size_t)k * HDIM];
        s += __shfl_xor(s, 1); s += __shfl_xor(s, 2);
        s += __shfl_xor(s, 4); s += __shfl_xor(s, 8);
        s *= 0.125f;
        float mn = fmaxf(m, s);
        float cr = __expf(m - mn), p = __expf(s - mn);
        l = l * cr + p;
        acc = acc * cr + p * Vg[(size_t)k * HDIM];
        m = mn;
    }
    O3[(size_t)g * HDIM + lane] = acc / l;
}

// -------------------------------------------- MAB epilogue: o = AO + Q ; out = o + relu(o@W + b)
// NQ = 0: Q per-row; NQ = 1: single shared row; NQ = 128: shared, row & 127
template<int NQ>
__global__ __launch_bounds__(256) void k_mab_epi(
    const float* __restrict__ AO, const float* __restrict__ Qsrc,
    const float* __restrict__ W, const float* __restrict__ bias,
    float* __restrict__ out, int M)
{
    constexpr int TM = 128, KK = 64, CO = 64, WTS = KK + 4;
    __shared__ float Os[TM * KK];
    __shared__ float Wt[CO * WTS];
    const int tid = threadIdx.x;
    const int row0 = blockIdx.x * TM;
    for (int i = tid; i < KK * CO; i += 256) {
        int k = i >> 6, c = i & 63;
        Wt[c * WTS + k] = W[i];
    }
    for (int i = tid; i < TM * 16; i += 256) {
        int r = i >> 4, v = (i & 15) << 2;
        int gr = row0 + r;
        float4 a = make_float4(0.f, 0.f, 0.f, 0.f);
        if (gr < M) {
            float4 x = *(const float4*)(AO + (size_t)gr * KK + v);
            int qr = (NQ == 0) ? gr : (NQ == 1 ? 0 : (gr & (NQ - 1)));
            float4 qv = *(const float4*)(Qsrc + (size_t)qr * KK + v);
            a.x = x.x + qv.x; a.y = x.y + qv.y; a.z = x.z + qv.z; a.w = x.w + qv.w;
        }
        *(float4*)(Os + r * KK + v) = a;
    }
    __syncthreads();
    const int co = tid & 63, g = tid >> 6;
    float4 wr[KK / 4];
#pragma unroll
    for (int kk = 0; kk < KK / 4; ++kk) wr[kk] = *(const float4*)(Wt + co * WTS + kk * 4);
    float acc[32];
#pragma unroll
    for (int r = 0; r < 32; ++r) acc[r] = 0.f;
    for (int kk = 0; kk < KK / 4; ++kk) {
        float4 w = wr[kk];
#pragma unroll
        for (int r = 0; r < 32; ++r) {
            float4 a = *(const float4*)(Os + (g * 32 + r) * KK + kk * 4);
            acc[r] += a.x * w.x + a.y * w.y + a.z * w.z + a.w * w.w;
        }
    }
    float b = bias[co];
#pragma unroll
    for (int r = 0; r < 32; ++r) {
        int gr = row0 + g * 32 + r;
        if (gr < M) {
            float o = Os[(g * 32 + r) * KK + co];
            out[(size_t)gr * CO + co] = o + fmaxf(acc[r] + b, 0.f);
        }
    }
}

// -------------------------------------------------------- final MLP head
// NOTE: d_out is FLOAT32 (reference output dtype) — round-2 failure was bf16 stores
// half-filling the f32 buffer (absmax == stub's 0.8789 signature).
__global__ __launch_bounds__(64) void k_head(
    const float* __restrict__ BX3,
    const float* __restrict__ W1, const float* __restrict__ b1,
    const float* __restrict__ W2, const float* __restrict__ b2,
    const float* __restrict__ W3, const float* __restrict__ b3,
    float* __restrict__ outp)
{
    __shared__ float w1[64 * 32], w2[32 * 16], w3[32], bb1[32], bb2[16], bb3[2];
    const int tid = threadIdx.x;
    for (int i = tid; i < 64 * 32; i += 64) w1[i] = W1[i];
    for (int i = tid; i < 32 * 16; i += 64) w2[i] = W2[i];
    if (tid < 32) { w3[tid] = W3[tid]; bb1[tid] = b1[tid]; }
    if (tid < 16) bb2[tid] = b2[tid];
    if (tid < 2)  bb3[tid] = b3[tid];
    __syncthreads();
    const int g = blockIdx.x * 64 + tid;
    float x[64];
#pragma unroll
    for (int v = 0; v < 16; ++v) {
        float4 t = *(const float4*)(BX3 + (size_t)g * 64 + v * 4);
        x[v*4] = t.x; x[v*4+1] = t.y; x[v*4+2] = t.z; x[v*4+3] = t.w;
    }
    float gv[32];
    for (int c = 0; c < 32; ++c) {
        float a = bb1[c];
        for (int k = 0; k < 64; ++k) a += x[k] * w1[k * 32 + c];
        gv[c] = a;
    }
    float h1[16];
    for (int c = 0; c < 16; ++c) {
        float a = bb2[c];
        for (int k = 0; k < 32; ++k) a += gv[k] * w2[k * 16 + c];
        h1[c] = fmaxf(a, 0.f);
    }
    float z0 = bb3[0], z1 = bb3[1];
    for (int k = 0; k < 16; ++k) { z0 += h1[k] * w3[k * 2]; z1 += h1[k] * w3[k * 2 + 1]; }
    float mm = fmaxf(z0, z1);
    float ls = mm + logf(__expf(z0 - mm) + __expf(z1 - mm));
    outp[g * 2]     = z0 - ls;
    outp[g * 2 + 1] = z1 - ls;
}

// =========================================================================
extern "C" void kernel_launch(void* const* d_in, const int* in_sizes, int n_in,
                              void* d_out, int out_size, void* d_ws, size_t ws_size,
                              hipStream_t stream) {
    const float* x0  = (const float*)d_in[0];
    const int*   ei  = (const int*)d_in[1];
    const float* c1W = (const float*)d_in[3];  const float* c1b = (const float*)d_in[4];
    const float* c2W = (const float*)d_in[5];  const float* c2b = (const float*)d_in[6];
    const float* c3W = (const float*)d_in[7];  const float* c3b = (const float*)d_in[8];
    const float* plW = (const float*)d_in[9];  const float* plb = (const float*)d_in[10];
    const float* S1  = (const float*)d_in[11];
    const float* p1Wq = (const float*)d_in[12]; const float* p1bq = (const float*)d_in[13];
    const float* p1Wk = (const float*)d_in[14]; const float* p1bk = (const float*)d_in[15];
    const float* p1Wv = (const float*)d_in[16]; const float* p1bv = (const float*)d_in[17];
    const float* p1Wo = (const float*)d_in[18]; const float* p1bo = (const float*)d_in[19];
    const float* sWq  = (const float*)d_in[20]; const float* sbq  = (const float*)d_in[21];
    const float* sWk  = (const float*)d_in[22]; const float* sbk  = (const float*)d_in[23];
    const float* sWv  = (const float*)d_in[24]; const float* sbv  = (const float*)d_in[25];
    const float* sWo  = (const float*)d_in[26]; const float* sbo  = (const float*)d_in[27];
    const float* p2Wq = (const float*)d_in[28]; const float* p2bq = (const float*)d_in[29];
    const float* p2Wk = (const float*)d_in[30]; const float* p2bk = (const float*)d_in[31];
    const float* p2Wv = (const float*)d_in[32]; const float* p2bv = (const float*)d_in[33];
    const float* p2Wo = (const float*)d_in[34]; const float* p2bo = (const float*)d_in[35];
    const float* S2   = (const float*)d_in[36];
    const float* pl2W = (const float*)d_in[37]; const float* pl2b = (const float*)d_in[38];
    const float* l1W  = (const float*)d_in[39]; const float* l1b  = (const float*)d_in[40];
    const float* l2W  = (const float*)d_in[41]; const float* l2b  = (const float*)d_in[42];

    const int* src = ei;
    const int* dst = ei + NEDGE;

    float* ws = (float*)d_ws;
    float* dinv = ws;                               // [N]
    size_t off = N_NODES;
    int* ssrc   = (int*)(ws + off); off += NEDGE;
    int* sdst   = (int*)(ws + off); off += NEDGE;
    int* cnt    = (int*)(ws + off); off += 256;
    int* starts = (int*)(ws + off); off += 257;
    int* cursor = (int*)(ws + off); off += 256;
    off = (off + 255) & ~(size_t)255;
    float* Qp  = ws + off; off += K1Q * HDIM;       // [128,64]
    float* Q2p = ws + off; off += HDIM;
    float* O3  = ws + off; off += NGRAPH * HDIM;
    float* BX3 = ws + off; off += NGRAPH * HDIM;
    off = (off + 1023) & ~(size_t)1023;
    float* P0 = ws + off;
    const size_t SL = (size_t)N_NODES * 32;         // one [N,32] slab
    float* T32 = P0;                // GEMM scratch [N,32]
    float* T64 = P0;                // GEMM scratch [N,64] (P0,P1)
    float* XC  = P0 + 2 * SL;       // [N,96] concat x1|x2|x3 (P2..P4)
    float* XL  = P0 + 5 * SL;       // [N,64] (P5,P6)
    float* KD  = P0 + 2 * SL;       // [N,64] (P2,P3)  - after XC dead
    float* VD  = P0 + 5 * SL;       // [N,64] (P5,P6)  - after XL dead
    float* O1  = P0 + 4 * SL;               // [B,128,64]
    float* BX1 = P0 + 4 * SL + SL / 2;      // [B,128,64]
    float* Qs  = P0;                        // SAB phase reuses P0..P3
    float* Ks_ = P0 + SL / 2;
    float* Vs_ = P0 + SL;
    float* O2  = P0 + SL + SL / 2;
    float* BX2 = P0 + 2 * SL;
    float* K3  = P0 + 2 * SL + SL / 2;
    float* V3  = P0 + 3 * SL;

    // degrees + dinv
    k_zero_f<<<512, 256, 0, stream>>>(dinv, N_NODES);
    k_deg_acc<<<4096, 256, 0, stream>>>(dst, dinv);
    k_dinv<<<512, 256, 0, stream>>>(dinv);

    // sort edges by graph
    k_zero_i<<<1, 256, 0, stream>>>(cnt, 256);
    k_hist<<<1024, 256, 0, stream>>>(dst, cnt);
    k_scan<<<1, 64, 0, stream>>>(cnt, starts, cursor);
    k_scatter<<<4096, 256, 0, stream>>>(src, dst, cursor, ssrc, sdst);

    // conv1/2/3 -> XC (stride 96)
    k_gemm<64, 128, 32, 0><<<2048, 256, 0, stream>>>(x0, FIN, c1W, nullptr, T32, 32, N_NODES);
    k_gcn_agg<1><<<256, 256, 0, stream>>>(T32, 32, dinv, c1b, ssrc, sdst, starts, XC, 96);
    k_gemm<128, 32, 32, 0><<<1024, 256, 0, stream>>>(XC, 96, c2W, nullptr, T32, 32, N_NODES);
    k_gcn_agg<1><<<256, 256, 0, stream>>>(T32, 32, dinv, c2b, ssrc, sdst, starts, XC + 32, 96);
    k_gemm<128, 32, 32, 0><<<1024, 256, 0, stream>>>(XC + 32, 96, c3W, nullptr, T32, 32, N_NODES);
    k_gcn_agg<1><<<256, 256, 0, stream>>>(T32, 32, dinv, c3b, ssrc, sdst, starts, XC + 64, 96);

    // xl = concat @ plW + plb
    k_gemm<64, 96, 64, 1><<<2048, 256, 0, stream>>>(XC, 96, plW, plb, XL, 64, N_NODES);

    // K/V GCN convs -> KD, VD
    k_gemm<128, 64, 64, 0><<<1024, 256, 0, stream>>>(XL, 64, p1Wk, nullptr, T64, 64, N_NODES);
    k_gcn_agg<0><<<256, 256, 0, stream>>>(T64, 64, dinv, p1bk, ssrc, sdst, starts, KD, 64);
    k_gcn_agg<0><<<256, 256, 0, stream>>>(T64 + 32, 64, dinv, p1bk + 32, ssrc, sdst, starts, KD + 32, 64);
    k_gemm<128, 64, 64, 0><<<1024, 256, 0, stream>>>(XL, 64, p1Wv, nullptr, T64, 64, N_NODES);
    k_gcn_agg<0><<<256, 256, 0, stream>>>(T64, 64, dinv, p1bv, ssrc, sdst, starts, VD, 64);
    k_gcn_agg<0><<<256, 256, 0, stream>>>(T64 + 32, 64, dinv, p1bv + 32, ssrc, sdst, starts, VD + 32, 64);

    // MAB1 (PMA with 128 seeds)
    k_gemm<128, 64, 64, 1><<<1, 256, 0, stream>>>(S1, 64, p1Wq, p1bq, Qp, 64, K1Q);
    k_attn<512, true><<<NGRAPH * 4, 128, 0, stream>>>(Qp, KD, VD, O1);
    k_mab_epi<128><<<256, 256, 0, stream>>>(O1, Qp, p1Wo, p1bo, BX1, NGRAPH * K1Q);

    // SAB
    k_gemm<128, 64, 64, 1><<<256, 256, 0, stream>>>(BX1, 64, sWq, sbq, Qs, 64, NGRAPH * K1Q);
    k_gemm<128, 64, 64, 1><<<256, 256, 0, stream>>>(BX1, 64, sWk, sbk, Ks_, 64, NGRAPH * K1Q);
    k_gemm<128, 64, 64, 1><<<256, 256, 0, stream>>>(BX1, 64, sWv, sbv, Vs_, 64, NGRAPH * K1Q);
    k_attn<128, false><<<NGRAPH * 4, 128, 0, stream>>>(Qs, Ks_, Vs_, O2);
    k_mab_epi<0><<<256, 256, 0, stream>>>(O2, Qs, sWo, sbo, BX2, NGRAPH * K1Q);

    // PMA2 (single seed)
    k_gemm<128, 64, 64, 1><<<256, 256, 0, stream>>>(BX2, 64, p2Wk, p2bk, K3, 64, NGRAPH * K1Q);
    k_gemm<128, 64, 64, 1><<<256, 256, 0, stream>>>(BX2, 64, p2Wv, p2bv, V3, 64, NGRAPH * K1Q);
    k_gemm<128, 64, 64, 1><<<1, 256, 0, stream>>>(S2, 64, p2Wq, p2bq, Q2p, 64, 1);
    k_attn_pma2<<<64, 256, 0, stream>>>(Q2p, K3, V3, O3);
    k_mab_epi<1><<<2, 256, 0, stream>>>(O3, Q2p, p2Wo, p2bo, BX3, NGRAPH);

    // head
    k_head<<<4, 64, 0, stream>>>(BX3, pl2W, pl2b, l1W, l1b, l2W, l2b,
                                 (float*)d_out);
}

// Round 4
// 2772.588 us; speedup vs baseline: 2.8192x; 2.8192x over previous
//
#include <hip/hip_runtime.h>
#include <hip/hip_bf16.h>

#define N_NODES 131072
#define NGRAPH  256
#define NMAXN   512
#define NEDGE   1048576
#define FIN     128
#define HDIM    64
#define K1Q     128

// ---------------------------------------------------------------- utilities
__global__ void k_zero_f(float* __restrict__ p, int n) {
    int i = blockIdx.x * blockDim.x + threadIdx.x;
    if (i < n) p[i] = 0.f;
}
__global__ void k_zero_i(int* __restrict__ p, int n) {
    int i = blockIdx.x * blockDim.x + threadIdx.x;
    if (i < n) p[i] = 0;
}

// degree = (# in-edges) ; dinv = rsqrt(deg+1)
__global__ void k_deg_acc(const int* __restrict__ dst, float* __restrict__ deg) {
    int e = blockIdx.x * blockDim.x + threadIdx.x;
    if (e < NEDGE) atomicAdd(&deg[dst[e]], 1.0f);
}
__global__ void k_dinv(float* __restrict__ d) {
    int i = blockIdx.x * blockDim.x + threadIdx.x;
    if (i < N_NODES) d[i] = rsqrtf(d[i] + 1.0f);
}

// ------------------------------------------------- edge sort by graph (dst>>9)
__global__ void k_hist(const int* __restrict__ dst, int* __restrict__ cnt) {
    __shared__ int h[NGRAPH];
    for (int i = threadIdx.x; i < NGRAPH; i += blockDim.x) h[i] = 0;
    __syncthreads();
    int base = blockIdx.x * blockDim.x * 4;
    for (int j = 0; j < 4; ++j) {
        int e = base + j * blockDim.x + threadIdx.x;
        if (e < NEDGE) atomicAdd(&h[dst[e] >> 9], 1);
    }
    __syncthreads();
    for (int i = threadIdx.x; i < NGRAPH; i += blockDim.x) atomicAdd(&cnt[i], h[i]);
}
__global__ void k_scan(const int* __restrict__ cnt, int* __restrict__ starts,
                       int* __restrict__ cursor) {
    if (threadIdx.x == 0) {
        int s = 0;
        for (int g = 0; g < NGRAPH; ++g) { starts[g] = s; cursor[g] = s; s += cnt[g]; }
        starts[NGRAPH] = s;
    }
}
__global__ void k_scatter(const int* __restrict__ src, const int* __restrict__ dst,
                          int* __restrict__ cursor, int* __restrict__ ssrc,
                          int* __restrict__ sdst) {
    int e = blockIdx.x * blockDim.x + threadIdx.x;
    if (e < NEDGE) {
        int d = dst[e];
        int p = atomicAdd(&cursor[d >> 9], 1);
        ssrc[p] = src[e];
        sdst[p] = d;
    }
}

// ------------------------------------------------------------- generic GEMM
// out[M,CO] = A[M,K] @ W[K,CO] (+bias) (+relu). A strided by lda, out by ldo.
// MODE: 0 = plain, 1 = +bias, 2 = +bias+relu
// W float4 is read from LDS inside the k-loop (NOT preloaded to registers):
// round-3 profile showed wr[K/4] preload -> 256 VGPR + 2.3 GB spill traffic.
template<int TM, int K, int CO, int MODE>
__global__ __launch_bounds__(256) void k_gemm(
    const float* __restrict__ A, int lda,
    const float* __restrict__ W, const float* __restrict__ bias,
    float* __restrict__ out, int ldo, int M)
{
    constexpr int WTS = K + 4;
    __shared__ float As[TM * K];
    __shared__ float Wt[CO * WTS];
    const int tid = threadIdx.x;
    const int row0 = blockIdx.x * TM;

    for (int i = tid; i < K * CO; i += 256) {
        int k = i / CO, c = i - k * CO;
        Wt[c * WTS + k] = W[i];
    }
    constexpr int VR = K / 4;
    for (int i = tid; i < TM * VR; i += 256) {
        int r = i / VR, v = i - r * VR;
        int gr = row0 + r;
        float4 val = make_float4(0.f, 0.f, 0.f, 0.f);
        if (gr < M) val = *(const float4*)(A + (size_t)gr * lda + v * 4);
        *(float4*)(As + r * K + v * 4) = val;
    }
    __syncthreads();

    constexpr int G = 256 / CO;
    constexpr int RPT = TM / G;
    const int co = tid % CO;
    const int g = tid / CO;

    float acc[RPT];
#pragma unroll
    for (int r = 0; r < RPT; ++r) acc[r] = 0.f;

    const float* wrow = Wt + co * WTS;
    for (int kk = 0; kk < K / 4; ++kk) {
        float4 w = *(const float4*)(wrow + kk * 4);
#pragma unroll
        for (int r = 0; r < RPT; ++r) {
            float4 a = *(const float4*)(As + (g * RPT + r) * K + kk * 4);
            acc[r] += a.x * w.x + a.y * w.y + a.z * w.z + a.w * w.w;
        }
    }
    float b = 0.f;
    if (MODE >= 1) b = bias[co];
#pragma unroll
    for (int r = 0; r < RPT; ++r) {
        int gr = row0 + g * RPT + r;
        if (gr < M) {
            float v = acc[r] + b;
            if (MODE == 2) v = fmaxf(v, 0.f);
            out[(size_t)gr * ldo + co] = v;
        }
    }
}

// --------------------------------------- GCN aggregation (per-graph, LDS atomics)
// out[n] = bias + T[n]*dinv[n]^2 + sum_{e: dst=n} T[src]*dinv[src]*dinv[dst]
// Processes 32 columns; pointers T/bias/out pre-offset by the column offset.
template<int RELU>
__global__ __launch_bounds__(256) void k_gcn_agg(
    const float* __restrict__ T, int ldt,
    const float* __restrict__ dinv, const float* __restrict__ bias,
    const int* __restrict__ ssrc, const int* __restrict__ sdst,
    const int* __restrict__ starts,
    float* __restrict__ out, int ldo)
{
    constexpr int LS = 36;                 // padded row stride (banks)
    __shared__ float Tl[NMAXN * LS];
    __shared__ float Ac[NMAXN * LS];
    __shared__ float dl[NMAXN];
    const int g = blockIdx.x;
    const int tid = threadIdx.x;
    const int node0 = g * NMAXN;

    for (int i = tid; i < NMAXN; i += 256) dl[i] = dinv[node0 + i];
    __syncthreads();
    for (int i = tid; i < NMAXN * 8; i += 256) {
        int r = i >> 3, c4 = (i & 7) << 2;
        float4 v = *(const float4*)(T + (size_t)(node0 + r) * ldt + c4);
        *(float4*)(Tl + r * LS + c4) = v;
        float w = dl[r] * dl[r];
        float4 b4 = *(const float4*)(bias + c4);
        float4 a;
        a.x = v.x * w + b4.x; a.y = v.y * w + b4.y;
        a.z = v.z * w + b4.z; a.w = v.w * w + b4.w;
        *(float4*)(Ac + r * LS + c4) = a;
    }
    __syncthreads();
    const int e0 = starts[g], e1 = starts[g + 1];
    const int nit = (e1 - e0) << 3;
    for (int i = tid; i < nit; i += 256) {
        int e = e0 + (i >> 3), c4 = (i & 7) << 2;
        int ls = ssrc[e] & (NMAXN - 1), ld = sdst[e] & (NMAXN - 1);
        float w = dl[ls] * dl[ld];
        float4 v = *(const float4*)(Tl + ls * LS + c4);
        float* ap = Ac + ld * LS + c4;
        atomicAdd(ap + 0, v.x * w); atomicAdd(ap + 1, v.y * w);
        atomicAdd(ap + 2, v.z * w); atomicAdd(ap + 3, v.w * w);
    }
    __syncthreads();
    for (int i = tid; i < NMAXN * 8; i += 256) {
        int r = i >> 3, c4 = (i & 7) << 2;
        float4 a = *(const float4*)(Ac + r * LS + c4);
        if (RELU) {
            a.x = fmaxf(a.x, 0.f); a.y = fmaxf(a.y, 0.f);
            a.z = fmaxf(a.z, 0.f); a.w = fmaxf(a.w, 0.f);
        }
        *(float4*)(out + (size_t)(node0 + r) * ldo + c4) = a;
    }
}

// ------------------------------------------------------ attention (flash-style)
// grid = NGRAPH*4 blocks (graph, head); block = 128 threads = one query each.
// Writes O[g, q, h*16+d] = softmax(QK^T/8) V   (no residual here)
template<int NK, bool QSH>
__global__ __launch_bounds__(128) void k_attn(
    const float* __restrict__ Q, const float* __restrict__ K,
    const float* __restrict__ V, float* __restrict__ O)
{
    __shared__ float Ks[NK * 16];
    __shared__ float Vs[NK * 16];
    const int g = blockIdx.x >> 2;
    const int h = blockIdx.x & 3;
    const int tid = threadIdx.x;
    for (int i = tid; i < NK * 4; i += 128) {
        int k = i >> 2, dc = (i & 3) << 2;
        const size_t off = ((size_t)g * NK + k) * HDIM + h * 16 + dc;
        *(float4*)(Ks + k * 16 + dc) = *(const float4*)(K + off);
        *(float4*)(Vs + k * 16 + dc) = *(const float4*)(V + off);
    }
    __syncthreads();
    const int q = tid;
    const float* qp = QSH ? (Q + (size_t)q * HDIM + h * 16)
                          : (Q + ((size_t)g * K1Q + q) * HDIM + h * 16);
    float qv[16];
#pragma unroll
    for (int d = 0; d < 16; ++d) qv[d] = qp[d];

    float m0 = -1e30f, l0 = 0.f, m1 = -1e30f, l1 = 0.f;
    float acc0[16], acc1[16];
#pragma unroll
    for (int d = 0; d < 16; ++d) { acc0[d] = 0.f; acc1[d] = 0.f; }

    for (int k = 0; k < NK; k += 2) {
        float s0 = 0.f, s1 = 0.f;
#pragma unroll
        for (int d4 = 0; d4 < 4; ++d4) {
            float4 ka = *(const float4*)(Ks + k * 16 + d4 * 4);
            float4 kb = *(const float4*)(Ks + (k + 1) * 16 + d4 * 4);
            s0 += qv[d4*4] * ka.x + qv[d4*4+1] * ka.y + qv[d4*4+2] * ka.z + qv[d4*4+3] * ka.w;
            s1 += qv[d4*4] * kb.x + qv[d4*4+1] * kb.y + qv[d4*4+2] * kb.z + qv[d4*4+3] * kb.w;
        }
        s0 *= 0.125f; s1 *= 0.125f;
        float mn0 = fmaxf(m0, s0);
        float cr0 = __expf(m0 - mn0), p0 = __expf(s0 - mn0);
        l0 = l0 * cr0 + p0; m0 = mn0;
        float mn1 = fmaxf(m1, s1);
        float cr1 = __expf(m1 - mn1), p1 = __expf(s1 - mn1);
        l1 = l1 * cr1 + p1; m1 = mn1;
#pragma unroll
        for (int d4 = 0; d4 < 4; ++d4) {
            float4 va = *(const float4*)(Vs + k * 16 + d4 * 4);
            float4 vb = *(const float4*)(Vs + (k + 1) * 16 + d4 * 4);
            acc0[d4*4]   = acc0[d4*4]   * cr0 + p0 * va.x;
            acc0[d4*4+1] = acc0[d4*4+1] * cr0 + p0 * va.y;
            acc0[d4*4+2] = acc0[d4*4+2] * cr0 + p0 * va.z;
            acc0[d4*4+3] = acc0[d4*4+3] * cr0 + p0 * va.w;
            acc1[d4*4]   = acc1[d4*4]   * cr1 + p1 * vb.x;
            acc1[d4*4+1] = acc1[d4*4+1] * cr1 + p1 * vb.y;
            acc1[d4*4+2] = acc1[d4*4+2] * cr1 + p1 * vb.z;
            acc1[d4*4+3] = acc1[d4*4+3] * cr1 + p1 * vb.w;
        }
    }
    float mn = fmaxf(m0, m1);
    float c0 = __expf(m0 - mn), c1 = __expf(m1 - mn);
    float inv = 1.f / (l0 * c0 + l1 * c1);
    float* op = O + ((size_t)g * K1Q + q) * HDIM + h * 16;
#pragma unroll
    for (int d = 0; d < 16; ++d) op[d] = (acc0[d] * c0 + acc1[d] * c1) * inv;
}

// PMA2: 1 query, 128 keys. block = 256 = 4 graphs x 64 lanes (lane = h*16+d)
__global__ __launch_bounds__(256) void k_attn_pma2(
    const float* __restrict__ Q2p, const float* __restrict__ K3,
    const float* __restrict__ V3, float* __restrict__ O3)
{
    const int t = threadIdx.x;
    const int lane = t & 63;
    const int g = blockIdx.x * 4 + (t >> 6);
    const float q = Q2p[lane];
    const float* Kg = K3 + (size_t)g * 128 * HDIM + lane;
    const float* Vg = V3 + (size_t)g * 128 * HDIM + lane;
    float m = -1e30f, l = 0.f, acc = 0.f;
    for (int k = 0; k < 128; ++k) {
        float s = q * Kg[(size_t)k * HDIM];
        s += __shfl_xor(s, 1); s += __shfl_xor(s, 2);
        s += __shfl_xor(s, 4); s += __shfl_xor(s, 8);
        s *= 0.125f;
        float mn = fmaxf(m, s);
        float cr = __expf(m - mn), p = __expf(s - mn);
        l = l * cr + p;
        acc = acc * cr + p * Vg[(size_t)k * HDIM];
        m = mn;
    }
    O3[(size_t)g * HDIM + lane] = acc / l;
}

// -------------------------------------------- MAB epilogue: o = AO + Q ; out = o + relu(o@W + b)
// NQ = 0: Q per-row; NQ = 1: single shared row; NQ = 128: shared, row & 127
// W read from LDS in-loop (same spill mechanism as k_gemm).
template<int NQ>
__global__ __launch_bounds__(256) void k_mab_epi(
    const float* __restrict__ AO, const float* __restrict__ Qsrc,
    const float* __restrict__ W, const float* __restrict__ bias,
    float* __restrict__ out, int M)
{
    constexpr int TM = 128, KK = 64, CO = 64, WTS = KK + 4;
    __shared__ float Os[TM * KK];
    __shared__ float Wt[CO * WTS];
    const int tid = threadIdx.x;
    const int row0 = blockIdx.x * TM;
    for (int i = tid; i < KK * CO; i += 256) {
        int k = i >> 6, c = i & 63;
        Wt[c * WTS + k] = W[i];
    }
    for (int i = tid; i < TM * 16; i += 256) {
        int r = i >> 4, v = (i & 15) << 2;
        int gr = row0 + r;
        float4 a = make_float4(0.f, 0.f, 0.f, 0.f);
        if (gr < M) {
            float4 x = *(const float4*)(AO + (size_t)gr * KK + v);
            int qr = (NQ == 0) ? gr : (NQ == 1 ? 0 : (gr & (NQ - 1)));
            float4 qv = *(const float4*)(Qsrc + (size_t)qr * KK + v);
            a.x = x.x + qv.x; a.y = x.y + qv.y; a.z = x.z + qv.z; a.w = x.w + qv.w;
        }
        *(float4*)(Os + r * KK + v) = a;
    }
    __syncthreads();
    const int co = tid & 63, g = tid >> 6;
    float acc[32];
#pragma unroll
    for (int r = 0; r < 32; ++r) acc[r] = 0.f;
    const float* wrow = Wt + co * WTS;
    for (int kk = 0; kk < KK / 4; ++kk) {
        float4 w = *(const float4*)(wrow + kk * 4);
#pragma unroll
        for (int r = 0; r < 32; ++r) {
            float4 a = *(const float4*)(Os + (g * 32 + r) * KK + kk * 4);
            acc[r] += a.x * w.x + a.y * w.y + a.z * w.z + a.w * w.w;
        }
    }
    float b = bias[co];
#pragma unroll
    for (int r = 0; r < 32; ++r) {
        int gr = row0 + g * 32 + r;
        if (gr < M) {
            float o = Os[(g * 32 + r) * KK + co];
            out[(size_t)gr * CO + co] = o + fmaxf(acc[r] + b, 0.f);
        }
    }
}

// -------------------------------------------------------- final MLP head
// NOTE: d_out is FLOAT32 (reference output dtype).
__global__ __launch_bounds__(64) void k_head(
    const float* __restrict__ BX3,
    const float* __restrict__ W1, const float* __restrict__ b1,
    const float* __restrict__ W2, const float* __restrict__ b2,
    const float* __restrict__ W3, const float* __restrict__ b3,
    float* __restrict__ outp)
{
    __shared__ float w1[64 * 32], w2[32 * 16], w3[32], bb1[32], bb2[16], bb3[2];
    const int tid = threadIdx.x;
    for (int i = tid; i < 64 * 32; i += 64) w1[i] = W1[i];
    for (int i = tid; i < 32 * 16; i += 64) w2[i] = W2[i];
    if (tid < 32) { w3[tid] = W3[tid]; bb1[tid] = b1[tid]; }
    if (tid < 16) bb2[tid] = b2[tid];
    if (tid < 2)  bb3[tid] = b3[tid];
    __syncthreads();
    const int g = blockIdx.x * 64 + tid;
    float x[64];
#pragma unroll
    for (int v = 0; v < 16; ++v) {
        float4 t = *(const float4*)(BX3 + (size_t)g * 64 + v * 4);
        x[v*4] = t.x; x[v*4+1] = t.y; x[v*4+2] = t.z; x[v*4+3] = t.w;
    }
    float gv[32];
    for (int c = 0; c < 32; ++c) {
        float a = bb1[c];
        for (int k = 0; k < 64; ++k) a += x[k] * w1[k * 32 + c];
        gv[c] = a;
    }
    float h1[16];
    for (int c = 0; c < 16; ++c) {
        float a = bb2[c];
        for (int k = 0; k < 32; ++k) a += gv[k] * w2[k * 16 + c];
        h1[c] = fmaxf(a, 0.f);
    }
    float z0 = bb3[0], z1 = bb3[1];
    for (int k = 0; k < 16; ++k) { z0 += h1[k] * w3[k * 2]; z1 += h1[k] * w3[k * 2 + 1]; }
    float mm = fmaxf(z0, z1);
    float ls = mm + logf(__expf(z0 - mm) + __expf(z1 - mm));
    outp[g * 2]     = z0 - ls;
    outp[g * 2 + 1] = z1 - ls;
}

// =========================================================================
extern "C" void kernel_launch(void* const* d_in, const int* in_sizes, int n_in,
                              void* d_out, int out_size, void* d_ws, size_t ws_size,
                              hipStream_t stream) {
    const float* x0  = (const float*)d_in[0];
    const int*   ei  = (const int*)d_in[1];
    const float* c1W = (const float*)d_in[3];  const float* c1b = (const float*)d_in[4];
    const float* c2W = (const float*)d_in[5];  const float* c2b = (const float*)d_in[6];
    const float* c3W = (const float*)d_in[7];  const float* c3b = (const float*)d_in[8];
    const float* plW = (const float*)d_in[9];  const float* plb = (const float*)d_in[10];
    const float* S1  = (const float*)d_in[11];
    const float* p1Wq = (const float*)d_in[12]; const float* p1bq = (const float*)d_in[13];
    const float* p1Wk = (const float*)d_in[14]; const float* p1bk = (const float*)d_in[15];
    const float* p1Wv = (const float*)d_in[16]; const float* p1bv = (const float*)d_in[17];
    const float* p1Wo = (const float*)d_in[18]; const float* p1bo = (const float*)d_in[19];
    const float* sWq  = (const float*)d_in[20]; const float* sbq  = (const float*)d_in[21];
    const float* sWk  = (const float*)d_in[22]; const float* sbk  = (const float*)d_in[23];
    const float* sWv  = (const float*)d_in[24]; const float* sbv  = (const float*)d_in[25];
    const float* sWo  = (const float*)d_in[26]; const float* sbo  = (const float*)d_in[27];
    const float* p2Wq = (const float*)d_in[28]; const float* p2bq = (const float*)d_in[29];
    const float* p2Wk = (const float*)d_in[30]; const float* p2bk = (const float*)d_in[31];
    const float* p2Wv = (const float*)d_in[32]; const float* p2bv = (const float*)d_in[33];
    const float* p2Wo = (const float*)d_in[34]; const float* p2bo = (const float*)d_in[35];
    const float* S2   = (const float*)d_in[36];
    const float* pl2W = (const float*)d_in[37]; const float* pl2b = (const float*)d_in[38];
    const float* l1W  = (const float*)d_in[39]; const float* l1b  = (const float*)d_in[40];
    const float* l2W  = (const float*)d_in[41]; const float* l2b  = (const float*)d_in[42];

    const int* src = ei;
    const int* dst = ei + NEDGE;

    float* ws = (float*)d_ws;
    float* dinv = ws;                               // [N]
    size_t off = N_NODES;
    int* ssrc   = (int*)(ws + off); off += NEDGE;
    int* sdst   = (int*)(ws + off); off += NEDGE;
    int* cnt    = (int*)(ws + off); off += 256;
    int* starts = (int*)(ws + off); off += 257;
    int* cursor = (int*)(ws + off); off += 256;
    off = (off + 255) & ~(size_t)255;
    float* Qp  = ws + off; off += K1Q * HDIM;       // [128,64]
    float* Q2p = ws + off; off += HDIM;
    float* O3  = ws + off; off += NGRAPH * HDIM;
    float* BX3 = ws + off; off += NGRAPH * HDIM;
    off = (off + 1023) & ~(size_t)1023;
    float* P0 = ws + off;
    const size_t SL = (size_t)N_NODES * 32;         // one [N,32] slab
    float* T32 = P0;                // GEMM scratch [N,32]
    float* T64 = P0;                // GEMM scratch [N,64] (P0,P1)
    float* XC  = P0 + 2 * SL;       // [N,96] concat x1|x2|x3 (P2..P4)
    float* XL  = P0 + 5 * SL;       // [N,64] (P5,P6)
    float* KD  = P0 + 2 * SL;       // [N,64] (P2,P3)  - after XC dead
    float* VD  = P0 + 5 * SL;       // [N,64] (P5,P6)  - after XL dead
    float* O1  = P0 + 4 * SL;               // [B,128,64]
    float* BX1 = P0 + 4 * SL + SL / 2;      // [B,128,64]
    float* Qs  = P0;                        // SAB phase reuses P0..P3
    float* Ks_ = P0 + SL / 2;
    float* Vs_ = P0 + SL;
    float* O2  = P0 + SL + SL / 2;
    float* BX2 = P0 + 2 * SL;
    float* K3  = P0 + 2 * SL + SL / 2;
    float* V3  = P0 + 3 * SL;

    // degrees + dinv
    k_zero_f<<<512, 256, 0, stream>>>(dinv, N_NODES);
    k_deg_acc<<<4096, 256, 0, stream>>>(dst, dinv);
    k_dinv<<<512, 256, 0, stream>>>(dinv);

    // sort edges by graph
    k_zero_i<<<1, 256, 0, stream>>>(cnt, 256);
    k_hist<<<1024, 256, 0, stream>>>(dst, cnt);
    k_scan<<<1, 64, 0, stream>>>(cnt, starts, cursor);
    k_scatter<<<4096, 256, 0, stream>>>(src, dst, cursor, ssrc, sdst);

    // conv1/2/3 -> XC (stride 96)
    k_gemm<64, 128, 32, 0><<<2048, 256, 0, stream>>>(x0, FIN, c1W, nullptr, T32, 32, N_NODES);
    k_gcn_agg<1><<<256, 256, 0, stream>>>(T32, 32, dinv, c1b, ssrc, sdst, starts, XC, 96);
    k_gemm<128, 32, 32, 0><<<1024, 256, 0, stream>>>(XC, 96, c2W, nullptr, T32, 32, N_NODES);
    k_gcn_agg<1><<<256, 256, 0, stream>>>(T32, 32, dinv, c2b, ssrc, sdst, starts, XC + 32, 96);
    k_gemm<128, 32, 32, 0><<<1024, 256, 0, stream>>>(XC + 32, 96, c3W, nullptr, T32, 32, N_NODES);
    k_gcn_agg<1><<<256, 256, 0, stream>>>(T32, 32, dinv, c3b, ssrc, sdst, starts, XC + 64, 96);

    // xl = concat @ plW + plb
    k_gemm<64, 96, 64, 1><<<2048, 256, 0, stream>>>(XC, 96, plW, plb, XL, 64, N_NODES);

    // K/V GCN convs -> KD, VD
    k_gemm<128, 64, 64, 0><<<1024, 256, 0, stream>>>(XL, 64, p1Wk, nullptr, T64, 64, N_NODES);
    k_gcn_agg<0><<<256, 256, 0, stream>>>(T64, 64, dinv, p1bk, ssrc, sdst, starts, KD, 64);
    k_gcn_agg<0><<<256, 256, 0, stream>>>(T64 + 32, 64, dinv, p1bk + 32, ssrc, sdst, starts, KD + 32, 64);
    k_gemm<128, 64, 64, 0><<<1024, 256, 0, stream>>>(XL, 64, p1Wv, nullptr, T64, 64, N_NODES);
    k_gcn_agg<0><<<256, 256, 0, stream>>>(T64, 64, dinv, p1bv, ssrc, sdst, starts, VD, 64);
    k_gcn_agg<0><<<256, 256, 0, stream>>>(T64 + 32, 64, dinv, p1bv + 32, ssrc, sdst, starts, VD + 32, 64);

    // MAB1 (PMA with 128 seeds)
    k_gemm<128, 64, 64, 1><<<1, 256, 0, stream>>>(S1, 64, p1Wq, p1bq, Qp, 64, K1Q);
    k_attn<512, true><<<NGRAPH * 4, 128, 0, stream>>>(Qp, KD, VD, O1);
    k_mab_epi<128><<<256, 256, 0, stream>>>(O1, Qp, p1Wo, p1bo, BX1, NGRAPH * K1Q);

    // SAB
    k_gemm<128, 64, 64, 1><<<256, 256, 0, stream>>>(BX1, 64, sWq, sbq, Qs, 64, NGRAPH * K1Q);
    k_gemm<128, 64, 64, 1><<<256, 256, 0, stream>>>(BX1, 64, sWk, sbk, Ks_, 64, NGRAPH * K1Q);
    k_gemm<128, 64, 64, 1><<<256, 256, 0, stream>>>(BX1, 64, sWv, sbv, Vs_, 64, NGRAPH * K1Q);
    k_attn<128, false><<<NGRAPH * 4, 128, 0, stream>>>(Qs, Ks_, Vs_, O2);
    k_mab_epi<0><<<256, 256, 0, stream>>>(O2, Qs, sWo, sbo, BX2, NGRAPH * K1Q);

    // PMA2 (single seed)
    k_gemm<128, 64, 64, 1><<<256, 256, 0, stream>>>(BX2, 64, p2Wk, p2bk, K3, 64, NGRAPH * K1Q);
    k_gemm<128, 64, 64, 1><<<256, 256, 0, stream>>>(BX2, 64, p2Wv, p2bv, V3, 64, NGRAPH * K1Q);
    k_gemm<128, 64, 64, 1><<<1, 256, 0, stream>>>(S2, 64, p2Wq, p2bq, Q2p, 64, 1);
    k_attn_pma2<<<64, 256, 0, stream>>>(Q2p, K3, V3, O3);
    k_mab_epi<1><<<2, 256, 0, stream>>>(O3, Q2p, p2Wo, p2bo, BX3, NGRAPH);

    // head
    k_head<<<4, 64, 0, stream>>>(BX3, pl2W, pl2b, l1W, l1b, l2W, l2b,
                                 (float*)d_out);
}

// Round 5
// 2273.351 us; speedup vs baseline: 3.4383x; 1.2196x over previous
//
#include <hip/hip_runtime.h>
#include <hip/hip_bf16.h>

#define N_NODES 131072
#define NGRAPH  256
#define NMAXN   512
#define NEDGE   1048576
#define FIN     128
#define HDIM    64
#define K1Q     128
#define EPB     1024           // edges per sort block
#define NBLK    (NEDGE / EPB)  // 1024 sort blocks

// ---------------------------------------------------------------- utilities
__global__ void k_zero_f(float* __restrict__ p, int n) {
    int i = blockIdx.x * blockDim.x + threadIdx.x;
    if (i < n) p[i] = 0.f;
}

// degree = (# in-edges) ; dinv = rsqrt(deg+1)
__global__ void k_deg_acc(const int* __restrict__ dst, float* __restrict__ deg) {
    int e = blockIdx.x * blockDim.x + threadIdx.x;
    if (e < NEDGE) atomicAdd(&deg[dst[e]], 1.0f);
}
__global__ void k_dinv(float* __restrict__ d) {
    int i = blockIdx.x * blockDim.x + threadIdx.x;
    if (i < N_NODES) d[i] = rsqrtf(d[i] + 1.0f);
}

// -------------------- counting sort of edges by graph (atomic-free global) ----
// Pass 1: per-block LDS histogram -> h[block*256+bin]
__global__ __launch_bounds__(256) void k_hist2(const int* __restrict__ dst,
                                               int* __restrict__ h) {
    __shared__ int lh[NGRAPH];
    const int tid = threadIdx.x;
    lh[tid] = 0;
    __syncthreads();
    const int base = blockIdx.x * EPB;
#pragma unroll
    for (int j = 0; j < 4; ++j)
        atomicAdd(&lh[dst[base + j * 256 + tid] >> 9], 1);
    __syncthreads();
    h[blockIdx.x * 256 + tid] = lh[tid];
}

// Pass 2a: one block per bin; exclusive-scan h[*][bin] over NBLK blocks.
__global__ __launch_bounds__(256) void k_scan_bins(int* __restrict__ h,
                                                   int* __restrict__ binTot) {
    const int b = blockIdx.x;      // bin
    const int tid = threadIdx.x;   // handles blocks tid*4 .. tid*4+3
    int v[4], s = 0;
#pragma unroll
    for (int j = 0; j < 4; ++j) { v[j] = h[(tid * 4 + j) * 256 + b]; s += v[j]; }
    __shared__ int sc[256];
    sc[tid] = s;
    __syncthreads();
    for (int o = 1; o < 256; o <<= 1) {
        int t = (tid >= o) ? sc[tid - o] : 0;
        __syncthreads();
        sc[tid] += t;
        __syncthreads();
    }
    int run = sc[tid] - s;         // exclusive prefix of this thread's group
#pragma unroll
    for (int j = 0; j < 4; ++j) { int t = v[j]; h[(tid * 4 + j) * 256 + b] = run; run += t; }
    if (tid == 255) binTot[b] = sc[255];
}

// Pass 2b: starts[] = exclusive scan of binTot (one block)
__global__ __launch_bounds__(256) void k_binstart(const int* __restrict__ binTot,
                                                  int* __restrict__ starts) {
    const int tid = threadIdx.x;
    int v = binTot[tid];
    __shared__ int sc[256];
    sc[tid] = v;
    __syncthreads();
    for (int o = 1; o < 256; o <<= 1) {
        int t = (tid >= o) ? sc[tid - o] : 0;
        __syncthreads();
        sc[tid] += t;
        __syncthreads();
    }
    starts[tid] = sc[tid] - v;
    if (tid == 255) starts[256] = sc[255];
}

// Pass 3: place edges; LDS cursor per bin; pack (src&511)<<9 | (dst&511)
__global__ __launch_bounds__(256) void k_scatter2(const int* __restrict__ src,
                                                  const int* __restrict__ dst,
                                                  const int* __restrict__ h,
                                                  const int* __restrict__ starts,
                                                  int* __restrict__ epack) {
    __shared__ int base[NGRAPH];
    const int tid = threadIdx.x;
    base[tid] = h[blockIdx.x * 256 + tid] + starts[tid];
    __syncthreads();
    const int b0 = blockIdx.x * EPB;
#pragma unroll
    for (int j = 0; j < 4; ++j) {
        int e = b0 + j * 256 + tid;
        int d = dst[e];
        int pos = atomicAdd(&base[d >> 9], 1);
        epack[pos] = ((src[e] & (NMAXN - 1)) << 9) | (d & (NMAXN - 1));
    }
}

// ------------------------------------------------------------- generic GEMM
// out[M,CO] = A[M,K] @ W[K,CO] (+bias) (+relu). A strided by lda, out by ldo.
// MODE: 0 = plain, 1 = +bias, 2 = +bias+relu
// W float4 read from LDS inside the k-loop (NOT preloaded): register preload
// caused 256-VGPR spills (round-3 profile: 2.3 GB scratch writes/dispatch).
template<int TM, int K, int CO, int MODE>
__global__ __launch_bounds__(256) void k_gemm(
    const float* __restrict__ A, int lda,
    const float* __restrict__ W, const float* __restrict__ bias,
    float* __restrict__ out, int ldo, int M)
{
    constexpr int WTS = K + 4;
    __shared__ float As[TM * K];
    __shared__ float Wt[CO * WTS];
    const int tid = threadIdx.x;
    const int row0 = blockIdx.x * TM;

    for (int i = tid; i < K * CO; i += 256) {
        int k = i / CO, c = i - k * CO;
        Wt[c * WTS + k] = W[i];
    }
    constexpr int VR = K / 4;
    for (int i = tid; i < TM * VR; i += 256) {
        int r = i / VR, v = i - r * VR;
        int gr = row0 + r;
        float4 val = make_float4(0.f, 0.f, 0.f, 0.f);
        if (gr < M) val = *(const float4*)(A + (size_t)gr * lda + v * 4);
        *(float4*)(As + r * K + v * 4) = val;
    }
    __syncthreads();

    constexpr int G = 256 / CO;
    constexpr int RPT = TM / G;
    const int co = tid % CO;
    const int g = tid / CO;

    float acc[RPT];
#pragma unroll
    for (int r = 0; r < RPT; ++r) acc[r] = 0.f;

    const float* wrow = Wt + co * WTS;
    for (int kk = 0; kk < K / 4; ++kk) {
        float4 w = *(const float4*)(wrow + kk * 4);
#pragma unroll
        for (int r = 0; r < RPT; ++r) {
            float4 a = *(const float4*)(As + (g * RPT + r) * K + kk * 4);
            acc[r] += a.x * w.x + a.y * w.y + a.z * w.z + a.w * w.w;
        }
    }
    float b = 0.f;
    if (MODE >= 1) b = bias[co];
#pragma unroll
    for (int r = 0; r < RPT; ++r) {
        int gr = row0 + g * RPT + r;
        if (gr < M) {
            float v = acc[r] + b;
            if (MODE == 2) v = fmaxf(v, 0.f);
            out[(size_t)gr * ldo + co] = v;
        }
    }
}

// --------------------------------------- GCN aggregation (per-graph, LDS atomics)
// out[n] = bias + T[n]*dinv[n]^2 + sum_{e: dst=n} T[src]*dinv[src]*dinv[dst]
// Processes 32 columns; pointers T/bias/out pre-offset by the column offset.
// Edge list: packed epack[e] = (src_local<<9)|dst_local, grouped by graph.
template<int RELU>
__global__ __launch_bounds__(256) void k_gcn_agg(
    const float* __restrict__ T, int ldt,
    const float* __restrict__ dinv, const float* __restrict__ bias,
    const int* __restrict__ epk, const int* __restrict__ starts,
    float* __restrict__ out, int ldo)
{
    constexpr int LS = 36;                 // padded row stride (banks)
    __shared__ float Tl[NMAXN * LS];
    __shared__ float Ac[NMAXN * LS];
    __shared__ float dl[NMAXN];
    const int g = blockIdx.x;
    const int tid = threadIdx.x;
    const int node0 = g * NMAXN;

    for (int i = tid; i < NMAXN; i += 256) dl[i] = dinv[node0 + i];
    __syncthreads();
    for (int i = tid; i < NMAXN * 8; i += 256) {
        int r = i >> 3, c4 = (i & 7) << 2;
        float4 v = *(const float4*)(T + (size_t)(node0 + r) * ldt + c4);
        *(float4*)(Tl + r * LS + c4) = v;
        float w = dl[r] * dl[r];
        float4 b4 = *(const float4*)(bias + c4);
        float4 a;
        a.x = v.x * w + b4.x; a.y = v.y * w + b4.y;
        a.z = v.z * w + b4.z; a.w = v.w * w + b4.w;
        *(float4*)(Ac + r * LS + c4) = a;
    }
    __syncthreads();
    const int e0 = starts[g], e1 = starts[g + 1];
    const int nit = (e1 - e0) << 3;
    for (int i = tid; i < nit; i += 256) {
        int e = e0 + (i >> 3), c4 = (i & 7) << 2;
        int ep = epk[e];
        int ls = ep >> 9, ld = ep & (NMAXN - 1);
        float w = dl[ls] * dl[ld];
        float4 v = *(const float4*)(Tl + ls * LS + c4);
        float* ap = Ac + ld * LS + c4;
        atomicAdd(ap + 0, v.x * w); atomicAdd(ap + 1, v.y * w);
        atomicAdd(ap + 2, v.z * w); atomicAdd(ap + 3, v.w * w);
    }
    __syncthreads();
    for (int i = tid; i < NMAXN * 8; i += 256) {
        int r = i >> 3, c4 = (i & 7) << 2;
        float4 a = *(const float4*)(Ac + r * LS + c4);
        if (RELU) {
            a.x = fmaxf(a.x, 0.f); a.y = fmaxf(a.y, 0.f);
            a.z = fmaxf(a.z, 0.f); a.w = fmaxf(a.w, 0.f);
        }
        *(float4*)(out + (size_t)(node0 + r) * ldo + c4) = a;
    }
}

// ------------------------------------------------------ attention (flash-style)
// grid = NGRAPH*4 blocks (graph, head); block = 128 threads = one query each.
// Writes O[g, q, h*16+d] = softmax(QK^T/8) V   (no residual here)
template<int NK, bool QSH>
__global__ __launch_bounds__(128) void k_attn(
    const float* __restrict__ Q, const float* __restrict__ K,
    const float* __restrict__ V, float* __restrict__ O)
{
    __shared__ float Ks[NK * 16];
    __shared__ float Vs[NK * 16];
    const int g = blockIdx.x >> 2;
    const int h = blockIdx.x & 3;
    const int tid = threadIdx.x;
    for (int i = tid; i < NK * 4; i += 128) {
        int k = i >> 2, dc = (i & 3) << 2;
        const size_t off = ((size_t)g * NK + k) * HDIM + h * 16 + dc;
        *(float4*)(Ks + k * 16 + dc) = *(const float4*)(K + off);
        *(float4*)(Vs + k * 16 + dc) = *(const float4*)(V + off);
    }
    __syncthreads();
    const int q = tid;
    const float* qp = QSH ? (Q + (size_t)q * HDIM + h * 16)
                          : (Q + ((size_t)g * K1Q + q) * HDIM + h * 16);
    float qv[16];
#pragma unroll
    for (int d = 0; d < 16; ++d) qv[d] = qp[d];

    float m0 = -1e30f, l0 = 0.f, m1 = -1e30f, l1 = 0.f;
    float acc0[16], acc1[16];
#pragma unroll
    for (int d = 0; d < 16; ++d) { acc0[d] = 0.f; acc1[d] = 0.f; }

    for (int k = 0; k < NK; k += 2) {
        float s0 = 0.f, s1 = 0.f;
#pragma unroll
        for (int d4 = 0; d4 < 4; ++d4) {
            float4 ka = *(const float4*)(Ks + k * 16 + d4 * 4);
            float4 kb = *(const float4*)(Ks + (k + 1) * 16 + d4 * 4);
            s0 += qv[d4*4] * ka.x + qv[d4*4+1] * ka.y + qv[d4*4+2] * ka.z + qv[d4*4+3] * ka.w;
            s1 += qv[d4*4] * kb.x + qv[d4*4+1] * kb.y + qv[d4*4+2] * kb.z + qv[d4*4+3] * kb.w;
        }
        s0 *= 0.125f; s1 *= 0.125f;
        float mn0 = fmaxf(m0, s0);
        float cr0 = __expf(m0 - mn0), p0 = __expf(s0 - mn0);
        l0 = l0 * cr0 + p0; m0 = mn0;
        float mn1 = fmaxf(m1, s1);
        float cr1 = __expf(m1 - mn1), p1 = __expf(s1 - mn1);
        l1 = l1 * cr1 + p1; m1 = mn1;
#pragma unroll
        for (int d4 = 0; d4 < 4; ++d4) {
            float4 va = *(const float4*)(Vs + k * 16 + d4 * 4);
            float4 vb = *(const float4*)(Vs + (k + 1) * 16 + d4 * 4);
            acc0[d4*4]   = acc0[d4*4]   * cr0 + p0 * va.x;
            acc0[d4*4+1] = acc0[d4*4+1] * cr0 + p0 * va.y;
            acc0[d4*4+2] = acc0[d4*4+2] * cr0 + p0 * va.z;
            acc0[d4*4+3] = acc0[d4*4+3] * cr0 + p0 * va.w;
            acc1[d4*4]   = acc1[d4*4]   * cr1 + p1 * vb.x;
            acc1[d4*4+1] = acc1[d4*4+1] * cr1 + p1 * vb.y;
            acc1[d4*4+2] = acc1[d4*4+2] * cr1 + p1 * vb.z;
            acc1[d4*4+3] = acc1[d4*4+3] * cr1 + p1 * vb.w;
        }
    }
    float mn = fmaxf(m0, m1);
    float c0 = __expf(m0 - mn), c1 = __expf(m1 - mn);
    float inv = 1.f / (l0 * c0 + l1 * c1);
    float* op = O + ((size_t)g * K1Q + q) * HDIM + h * 16;
#pragma unroll
    for (int d = 0; d < 16; ++d) op[d] = (acc0[d] * c0 + acc1[d] * c1) * inv;
}

// PMA2: 1 query, 128 keys. block = 256 = 4 graphs x 64 lanes (lane = h*16+d)
__global__ __launch_bounds__(256) void k_attn_pma2(
    const float* __restrict__ Q2p, const float* __restrict__ K3,
    const float* __restrict__ V3, float* __restrict__ O3)
{
    const int t = threadIdx.x;
    const int lane = t & 63;
    const int g = blockIdx.x * 4 + (t >> 6);
    const float q = Q2p[lane];
    const float* Kg = K3 + (size_t)g * 128 * HDIM + lane;
    const float* Vg = V3 + (size_t)g * 128 * HDIM + lane;
    float m = -1e30f, l = 0.f, acc = 0.f;
    for (int k = 0; k < 128; ++k) {
        float s = q * Kg[(size_t)k * HDIM];
        s += __shfl_xor(s, 1); s += __shfl_xor(s, 2);
        s += __shfl_xor(s, 4); s += __shfl_xor(s, 8);
        s *= 0.125f;
        float mn = fmaxf(m, s);
        float cr = __expf(m - mn), p = __expf(s - mn);
        l = l * cr + p;
        acc = acc * cr + p * Vg[(size_t)k * HDIM];
        m = mn;
    }
    O3[(size_t)g * HDIM + lane] = acc / l;
}

// -------------------------------------------- MAB epilogue: o = AO + Q ; out = o + relu(o@W + b)
// NQ = 0: Q per-row; NQ = 1: single shared row; NQ = 128: shared, row & 127
// W read from LDS in-loop (same spill mechanism as k_gemm).
template<int NQ>
__global__ __launch_bounds__(256) void k_mab_epi(
    const float* __restrict__ AO, const float* __restrict__ Qsrc,
    const float* __restrict__ W, const float* __restrict__ bias,
    float* __restrict__ out, int M)
{
    constexpr int TM = 128, KK = 64, CO = 64, WTS = KK + 4;
    __shared__ float Os[TM * KK];
    __shared__ float Wt[CO * WTS];
    const int tid = threadIdx.x;
    const int row0 = blockIdx.x * TM;
    for (int i = tid; i < KK * CO; i += 256) {
        int k = i >> 6, c = i & 63;
        Wt[c * WTS + k] = W[i];
    }
    for (int i = tid; i < TM * 16; i += 256) {
        int r = i >> 4, v = (i & 15) << 2;
        int gr = row0 + r;
        float4 a = make_float4(0.f, 0.f, 0.f, 0.f);
        if (gr < M) {
            float4 x = *(const float4*)(AO + (size_t)gr * KK + v);
            int qr = (NQ == 0) ? gr : (NQ == 1 ? 0 : (gr & (NQ - 1)));
            float4 qv = *(const float4*)(Qsrc + (size_t)qr * KK + v);
            a.x = x.x + qv.x; a.y = x.y + qv.y; a.z = x.z + qv.z; a.w = x.w + qv.w;
        }
        *(float4*)(Os + r * KK + v) = a;
    }
    __syncthreads();
    const int co = tid & 63, g = tid >> 6;
    float acc[32];
#pragma unroll
    for (int r = 0; r < 32; ++r) acc[r] = 0.f;
    const float* wrow = Wt + co * WTS;
    for (int kk = 0; kk < KK / 4; ++kk) {
        float4 w = *(const float4*)(wrow + kk * 4);
#pragma unroll
        for (int r = 0; r < 32; ++r) {
            float4 a = *(const float4*)(Os + (g * 32 + r) * KK + kk * 4);
            acc[r] += a.x * w.x + a.y * w.y + a.z * w.z + a.w * w.w;
        }
    }
    float b = bias[co];
#pragma unroll
    for (int r = 0; r < 32; ++r) {
        int gr = row0 + g * 32 + r;
        if (gr < M) {
            float o = Os[(g * 32 + r) * KK + co];
            out[(size_t)gr * CO + co] = o + fmaxf(acc[r] + b, 0.f);
        }
    }
}

// -------------------------------------------------------- final MLP head
// NOTE: d_out is FLOAT32 (reference output dtype).
__global__ __launch_bounds__(64) void k_head(
    const float* __restrict__ BX3,
    const float* __restrict__ W1, const float* __restrict__ b1,
    const float* __restrict__ W2, const float* __restrict__ b2,
    const float* __restrict__ W3, const float* __restrict__ b3,
    float* __restrict__ outp)
{
    __shared__ float w1[64 * 32], w2[32 * 16], w3[32], bb1[32], bb2[16], bb3[2];
    const int tid = threadIdx.x;
    for (int i = tid; i < 64 * 32; i += 64) w1[i] = W1[i];
    for (int i = tid; i < 32 * 16; i += 64) w2[i] = W2[i];
    if (tid < 32) { w3[tid] = W3[tid]; bb1[tid] = b1[tid]; }
    if (tid < 16) bb2[tid] = b2[tid];
    if (tid < 2)  bb3[tid] = b3[tid];
    __syncthreads();
    const int g = blockIdx.x * 64 + tid;
    float x[64];
#pragma unroll
    for (int v = 0; v < 16; ++v) {
        float4 t = *(const float4*)(BX3 + (size_t)g * 64 + v * 4);
        x[v*4] = t.x; x[v*4+1] = t.y; x[v*4+2] = t.z; x[v*4+3] = t.w;
    }
    float gv[32];
    for (int c = 0; c < 32; ++c) {
        float a = bb1[c];
        for (int k = 0; k < 64; ++k) a += x[k] * w1[k * 32 + c];
        gv[c] = a;
    }
    float h1[16];
    for (int c = 0; c < 16; ++c) {
        float a = bb2[c];
        for (int k = 0; k < 32; ++k) a += gv[k] * w2[k * 16 + c];
        h1[c] = fmaxf(a, 0.f);
    }
    float z0 = bb3[0], z1 = bb3[1];
    for (int k = 0; k < 16; ++k) { z0 += h1[k] * w3[k * 2]; z1 += h1[k] * w3[k * 2 + 1]; }
    float mm = fmaxf(z0, z1);
    float ls = mm + logf(__expf(z0 - mm) + __expf(z1 - mm));
    outp[g * 2]     = z0 - ls;
    outp[g * 2 + 1] = z1 - ls;
}

// =========================================================================
extern "C" void kernel_launch(void* const* d_in, const int* in_sizes, int n_in,
                              void* d_out, int out_size, void* d_ws, size_t ws_size,
                              hipStream_t stream) {
    const float* x0  = (const float*)d_in[0];
    const int*   ei  = (const int*)d_in[1];
    const float* c1W = (const float*)d_in[3];  const float* c1b = (const float*)d_in[4];
    const float* c2W = (const float*)d_in[5];  const float* c2b = (const float*)d_in[6];
    const float* c3W = (const float*)d_in[7];  const float* c3b = (const float*)d_in[8];
    const float* plW = (const float*)d_in[9];  const float* plb = (const float*)d_in[10];
    const float* S1  = (const float*)d_in[11];
    const float* p1Wq = (const float*)d_in[12]; const float* p1bq = (const float*)d_in[13];
    const float* p1Wk = (const float*)d_in[14]; const float* p1bk = (const float*)d_in[15];
    const float* p1Wv = (const float*)d_in[16]; const float* p1bv = (const float*)d_in[17];
    const float* p1Wo = (const float*)d_in[18]; const float* p1bo = (const float*)d_in[19];
    const float* sWq  = (const float*)d_in[20]; const float* sbq  = (const float*)d_in[21];
    const float* sWk  = (const float*)d_in[22]; const float* sbk  = (const float*)d_in[23];
    const float* sWv  = (const float*)d_in[24]; const float* sbv  = (const float*)d_in[25];
    const float* sWo  = (const float*)d_in[26]; const float* sbo  = (const float*)d_in[27];
    const float* p2Wq = (const float*)d_in[28]; const float* p2bq = (const float*)d_in[29];
    const float* p2Wk = (const float*)d_in[30]; const float* p2bk = (const float*)d_in[31];
    const float* p2Wv = (const float*)d_in[32]; const float* p2bv = (const float*)d_in[33];
    const float* p2Wo = (const float*)d_in[34]; const float* p2bo = (const float*)d_in[35];
    const float* S2   = (const float*)d_in[36];
    const float* pl2W = (const float*)d_in[37]; const float* pl2b = (const float*)d_in[38];
    const float* l1W  = (const float*)d_in[39]; const float* l1b  = (const float*)d_in[40];
    const float* l2W  = (const float*)d_in[41]; const float* l2b  = (const float*)d_in[42];

    const int* src = ei;
    const int* dst = ei + NEDGE;

    float* ws = (float*)d_ws;
    float* dinv = ws;                               // [N]
    size_t off = N_NODES;
    int* epack  = (int*)(ws + off); off += NEDGE;   // packed sorted edges
    int* h      = (int*)(ws + off); off += NBLK * 256;
    int* binTot = (int*)(ws + off); off += 256;
    int* starts = (int*)(ws + off); off += 257;
    off = (off + 255) & ~(size_t)255;
    float* Qp  = ws + off; off += K1Q * HDIM;       // [128,64]
    float* Q2p = ws + off; off += HDIM;
    float* O3  = ws + off; off += NGRAPH * HDIM;
    float* BX3 = ws + off; off += NGRAPH * HDIM;
    off = (off + 1023) & ~(size_t)1023;
    float* P0 = ws + off;
    const size_t SL = (size_t)N_NODES * 32;         // one [N,32] slab
    float* T32 = P0;                // GEMM scratch [N,32]
    float* T64 = P0;                // GEMM scratch [N,64] (P0,P1)
    float* XC  = P0 + 2 * SL;       // [N,96] concat x1|x2|x3 (P2..P4)
    float* XL  = P0 + 5 * SL;       // [N,64] (P5,P6)
    float* KD  = P0 + 2 * SL;       // [N,64] (P2,P3)  - after XC dead
    float* VD  = P0 + 5 * SL;       // [N,64] (P5,P6)  - after XL dead
    float* O1  = P0 + 4 * SL;               // [B,128,64]
    float* BX1 = P0 + 4 * SL + SL / 2;      // [B,128,64]
    float* Qs  = P0;                        // SAB phase reuses P0..P3
    float* Ks_ = P0 + SL / 2;
    float* Vs_ = P0 + SL;
    float* O2  = P0 + SL + SL / 2;
    float* BX2 = P0 + 2 * SL;
    float* K3  = P0 + 2 * SL + SL / 2;
    float* V3  = P0 + 3 * SL;

    // degrees + dinv
    k_zero_f<<<512, 256, 0, stream>>>(dinv, N_NODES);
    k_deg_acc<<<4096, 256, 0, stream>>>(dst, dinv);
    k_dinv<<<512, 256, 0, stream>>>(dinv);

    // counting sort of edges by graph (no global atomics)
    k_hist2<<<NBLK, 256, 0, stream>>>(dst, h);
    k_scan_bins<<<256, 256, 0, stream>>>(h, binTot);
    k_binstart<<<1, 256, 0, stream>>>(binTot, starts);
    k_scatter2<<<NBLK, 256, 0, stream>>>(src, dst, h, starts, epack);

    // conv1/2/3 -> XC (stride 96)
    k_gemm<64, 128, 32, 0><<<2048, 256, 0, stream>>>(x0, FIN, c1W, nullptr, T32, 32, N_NODES);
    k_gcn_agg<1><<<256, 256, 0, stream>>>(T32, 32, dinv, c1b, epack, starts, XC, 96);
    k_gemm<128, 32, 32, 0><<<1024, 256, 0, stream>>>(XC, 96, c2W, nullptr, T32, 32, N_NODES);
    k_gcn_agg<1><<<256, 256, 0, stream>>>(T32, 32, dinv, c2b, epack, starts, XC + 32, 96);
    k_gemm<128, 32, 32, 0><<<1024, 256, 0, stream>>>(XC + 32, 96, c3W, nullptr, T32, 32, N_NODES);
    k_gcn_agg<1><<<256, 256, 0, stream>>>(T32, 32, dinv, c3b, epack, starts, XC + 64, 96);

    // xl = concat @ plW + plb
    k_gemm<64, 96, 64, 1><<<2048, 256, 0, stream>>>(XC, 96, plW, plb, XL, 64, N_NODES);

    // K/V GCN convs -> KD, VD
    k_gemm<128, 64, 64, 0><<<1024, 256, 0, stream>>>(XL, 64, p1Wk, nullptr, T64, 64, N_NODES);
    k_gcn_agg<0><<<256, 256, 0, stream>>>(T64, 64, dinv, p1bk, epack, starts, KD, 64);
    k_gcn_agg<0><<<256, 256, 0, stream>>>(T64 + 32, 64, dinv, p1bk + 32, epack, starts, KD + 32, 64);
    k_gemm<128, 64, 64, 0><<<1024, 256, 0, stream>>>(XL, 64, p1Wv, nullptr, T64, 64, N_NODES);
    k_gcn_agg<0><<<256, 256, 0, stream>>>(T64, 64, dinv, p1bv, epack, starts, VD, 64);
    k_gcn_agg<0><<<256, 256, 0, stream>>>(T64 + 32, 64, dinv, p1bv + 32, epack, starts, VD + 32, 64);

    // MAB1 (PMA with 128 seeds)
    k_gemm<128, 64, 64, 1><<<1, 256, 0, stream>>>(S1, 64, p1Wq, p1bq, Qp, 64, K1Q);
    k_attn<512, true><<<NGRAPH * 4, 128, 0, stream>>>(Qp, KD, VD, O1);
    k_mab_epi<128><<<256, 256, 0, stream>>>(O1, Qp, p1Wo, p1bo, BX1, NGRAPH * K1Q);

    // SAB
    k_gemm<128, 64, 64, 1><<<256, 256, 0, stream>>>(BX1, 64, sWq, sbq, Qs, 64, NGRAPH * K1Q);
    k_gemm<128, 64, 64, 1><<<256, 256, 0, stream>>>(BX1, 64, sWk, sbk, Ks_, 64, NGRAPH * K1Q);
    k_gemm<128, 64, 64, 1><<<256, 256, 0, stream>>>(BX1, 64, sWv, sbv, Vs_, 64, NGRAPH * K1Q);
    k_attn<128, false><<<NGRAPH * 4, 128, 0, stream>>>(Qs, Ks_, Vs_, O2);
    k_mab_epi<0><<<256, 256, 0, stream>>>(O2, Qs, sWo, sbo, BX2, NGRAPH * K1Q);

    // PMA2 (single seed)
    k_gemm<128, 64, 64, 1><<<256, 256, 0, stream>>>(BX2, 64, p2Wk, p2bk, K3, 64, NGRAPH * K1Q);
    k_gemm<128, 64, 64, 1><<<256, 256, 0, stream>>>(BX2, 64, p2Wv, p2bv, V3, 64, NGRAPH * K1Q);
    k_gemm<128, 64, 64, 1><<<1, 256, 0, stream>>>(S2, 64, p2Wq, p2bq, Q2p, 64, 1);
    k_attn_pma2<<<64, 256, 0, stream>>>(Q2p, K3, V3, O3);
    k_mab_epi<1><<<2, 256, 0, stream>>>(O3, Q2p, p2Wo, p2bo, BX3, NGRAPH);

    // head
    k_head<<<4, 64, 0, stream>>>(BX3, pl2W, pl2b, l1W, l1b, l2W, l2b,
                                 (float*)d_out);
}

// Round 6
// 1181.832 us; speedup vs baseline: 6.6139x; 1.9236x over previous
//
#include <hip/hip_runtime.h>
#include <hip/hip_bf16.h>

#define N_NODES 131072
#define NGRAPH  256
#define NMAXN   512
#define NEDGE   1048576
#define FIN     128
#define HDIM    64
#define K1Q     128
#define EPB     1024           // edges per sort block
#define NBLK    (NEDGE / EPB)  // 1024 sort blocks

// -------------------- counting sort of edges by graph (atomic-free global) ----
// Pass 1: per-block LDS histogram -> h[block*256+bin]
__global__ __launch_bounds__(256) void k_hist2(const int* __restrict__ dst,
                                               int* __restrict__ h) {
    __shared__ int lh[NGRAPH];
    const int tid = threadIdx.x;
    lh[tid] = 0;
    __syncthreads();
    const int base = blockIdx.x * EPB;
#pragma unroll
    for (int j = 0; j < 4; ++j)
        atomicAdd(&lh[dst[base + j * 256 + tid] >> 9], 1);
    __syncthreads();
    h[blockIdx.x * 256 + tid] = lh[tid];
}

// Pass 2a: one block per bin; exclusive-scan h[*][bin] over NBLK blocks.
__global__ __launch_bounds__(256) void k_scan_bins(int* __restrict__ h,
                                                   int* __restrict__ binTot) {
    const int b = blockIdx.x;      // bin
    const int tid = threadIdx.x;   // handles blocks tid*4 .. tid*4+3
    int v[4], s = 0;
#pragma unroll
    for (int j = 0; j < 4; ++j) { v[j] = h[(tid * 4 + j) * 256 + b]; s += v[j]; }
    __shared__ int sc[256];
    sc[tid] = s;
    __syncthreads();
    for (int o = 1; o < 256; o <<= 1) {
        int t = (tid >= o) ? sc[tid - o] : 0;
        __syncthreads();
        sc[tid] += t;
        __syncthreads();
    }
    int run = sc[tid] - s;         // exclusive prefix of this thread's group
#pragma unroll
    for (int j = 0; j < 4; ++j) { int t = v[j]; h[(tid * 4 + j) * 256 + b] = run; run += t; }
    if (tid == 255) binTot[b] = sc[255];
}

// Pass 2b: starts[] = exclusive scan of binTot (one block)
__global__ __launch_bounds__(256) void k_binstart(const int* __restrict__ binTot,
                                                  int* __restrict__ starts) {
    const int tid = threadIdx.x;
    int v = binTot[tid];
    __shared__ int sc[256];
    sc[tid] = v;
    __syncthreads();
    for (int o = 1; o < 256; o <<= 1) {
        int t = (tid >= o) ? sc[tid - o] : 0;
        __syncthreads();
        sc[tid] += t;
        __syncthreads();
    }
    starts[tid] = sc[tid] - v;
    if (tid == 255) starts[256] = sc[255];
}

// Pass 3: place edges; LDS cursor per bin; pack (src&511)<<9 | (dst&511)
__global__ __launch_bounds__(256) void k_scatter2(const int* __restrict__ src,
                                                  const int* __restrict__ dst,
                                                  const int* __restrict__ h,
                                                  const int* __restrict__ starts,
                                                  int* __restrict__ epack) {
    __shared__ int base[NGRAPH];
    const int tid = threadIdx.x;
    base[tid] = h[blockIdx.x * 256 + tid] + starts[tid];
    __syncthreads();
    const int b0 = blockIdx.x * EPB;
#pragma unroll
    for (int j = 0; j < 4; ++j) {
        int e = b0 + j * 256 + tid;
        int d = dst[e];
        int pos = atomicAdd(&base[d >> 9], 1);
        epack[pos] = ((src[e] & (NMAXN - 1)) << 9) | (d & (NMAXN - 1));
    }
}

// Pass 4: within each graph, sort by dst-local -> CSR (rowptr + esrc).
// One block per graph; LDS histogram + scan; no global atomics.
__global__ __launch_bounds__(256) void k_sort_dst(
    const int* __restrict__ epack, const int* __restrict__ starts,
    int* __restrict__ esrc, int* __restrict__ rowptr)
{
    __shared__ int hist[NMAXN];
    __shared__ int excl[NMAXN];
    __shared__ int psc[256];
    const int g = blockIdx.x, tid = threadIdx.x;
    const int e0 = starts[g], e1 = starts[g + 1];
    hist[tid] = 0; hist[tid + 256] = 0;
    __syncthreads();
    for (int e = e0 + tid; e < e1; e += 256)
        atomicAdd(&hist[epack[e] & (NMAXN - 1)], 1);
    __syncthreads();
    int a = hist[2 * tid], b = hist[2 * tid + 1];
    psc[tid] = a + b;
    __syncthreads();
    for (int o = 1; o < 256; o <<= 1) {
        int t = (tid >= o) ? psc[tid - o] : 0;
        __syncthreads();
        psc[tid] += t;
        __syncthreads();
    }
    int ep = psc[tid] - a - b;     // exclusive pair prefix
    excl[2 * tid] = ep;
    excl[2 * tid + 1] = ep + a;
    __syncthreads();
    rowptr[g * NMAXN + 2 * tid]     = e0 + excl[2 * tid];
    rowptr[g * NMAXN + 2 * tid + 1] = e0 + excl[2 * tid + 1];
    if (g == NGRAPH - 1 && tid == 0) rowptr[N_NODES] = NEDGE;
    __syncthreads();
    for (int e = e0 + tid; e < e1; e += 256) {
        int p = epack[e];
        int d = p & (NMAXN - 1);
        int pos = e0 + atomicAdd(&excl[d], 1);
        esrc[pos] = p >> 9;
    }
}

// dinv from CSR degree (replaces zero+deg_acc+dinv: deg[n] = rowptr[n+1]-rowptr[n])
__global__ void k_dinv2(const int* __restrict__ rowptr, float* __restrict__ d) {
    int i = blockIdx.x * blockDim.x + threadIdx.x;
    if (i < N_NODES) d[i] = rsqrtf((float)(rowptr[i + 1] - rowptr[i]) + 1.0f);
}

// ------------------------------------------------------------- generic GEMM
// out[M,CO] = A[M,K] @ W[K,CO] (+bias) (+relu). A strided by lda, out by ldo.
// MODE: 0 = plain, 1 = +bias, 2 = +bias+relu
// W float4 read from LDS inside the k-loop (NOT preloaded): register preload
// caused 256-VGPR spills (round-3 profile: 2.3 GB scratch writes/dispatch).
template<int TM, int K, int CO, int MODE>
__global__ __launch_bounds__(256) void k_gemm(
    const float* __restrict__ A, int lda,
    const float* __restrict__ W, const float* __restrict__ bias,
    float* __restrict__ out, int ldo, int M)
{
    constexpr int WTS = K + 4;
    __shared__ float As[TM * K];
    __shared__ float Wt[CO * WTS];
    const int tid = threadIdx.x;
    const int row0 = blockIdx.x * TM;

    for (int i = tid; i < K * CO; i += 256) {
        int k = i / CO, c = i - k * CO;
        Wt[c * WTS + k] = W[i];
    }
    constexpr int VR = K / 4;
    for (int i = tid; i < TM * VR; i += 256) {
        int r = i / VR, v = i - r * VR;
        int gr = row0 + r;
        float4 val = make_float4(0.f, 0.f, 0.f, 0.f);
        if (gr < M) val = *(const float4*)(A + (size_t)gr * lda + v * 4);
        *(float4*)(As + r * K + v * 4) = val;
    }
    __syncthreads();

    constexpr int G = 256 / CO;
    constexpr int RPT = TM / G;
    const int co = tid % CO;
    const int g = tid / CO;

    float acc[RPT];
#pragma unroll
    for (int r = 0; r < RPT; ++r) acc[r] = 0.f;

    const float* wrow = Wt + co * WTS;
    for (int kk = 0; kk < K / 4; ++kk) {
        float4 w = *(const float4*)(wrow + kk * 4);
#pragma unroll
        for (int r = 0; r < RPT; ++r) {
            float4 a = *(const float4*)(As + (g * RPT + r) * K + kk * 4);
            acc[r] += a.x * w.x + a.y * w.y + a.z * w.z + a.w * w.w;
        }
    }
    float b = 0.f;
    if (MODE >= 1) b = bias[co];
#pragma unroll
    for (int r = 0; r < RPT; ++r) {
        int gr = row0 + g * RPT + r;
        if (gr < M) {
            float v = acc[r] + b;
            if (MODE == 2) v = fmaxf(v, 0.f);
            out[(size_t)gr * ldo + co] = v;
        }
    }
}

// --------------------------------------- GCN aggregation (CSR, atomic-free)
// out[n] = bias + dinv[n] * ( Tl[n] + sum_{e in row n} Tl[src_e] )
// where Tl[x] = T[x]*dinv[x] (premultiplied on LDS load). 32 columns per call.
template<int RELU>
__global__ __launch_bounds__(256) void k_gcn_agg2(
    const float* __restrict__ T, int ldt,
    const float* __restrict__ dinv, const float* __restrict__ bias,
    const int* __restrict__ esrc, const int* __restrict__ rowptr,
    float* __restrict__ out, int ldo)
{
    constexpr int LS = 36;                 // padded row stride (16B-aligned float4)
    __shared__ float Tl[NMAXN * LS];
    __shared__ float dl[NMAXN];
    const int g = blockIdx.x;
    const int tid = threadIdx.x;
    const int node0 = g * NMAXN;

    for (int i = tid; i < NMAXN; i += 256) dl[i] = dinv[node0 + i];
    __syncthreads();
    for (int i = tid; i < NMAXN * 8; i += 256) {
        int r = i >> 3, c4 = (i & 7) << 2;
        float4 v = *(const float4*)(T + (size_t)(node0 + r) * ldt + c4);
        float w = dl[r];
        v.x *= w; v.y *= w; v.z *= w; v.w *= w;
        *(float4*)(Tl + r * LS + c4) = v;
    }
    __syncthreads();
    // lanes 0-7 share node n (broadcast esrc reads, uniform run length)
    for (int i = tid; i < NMAXN * 8; i += 256) {
        int n = i >> 3, c4 = (i & 7) << 2;
        float4 acc = *(const float4*)(Tl + n * LS + c4);
        const int eb = rowptr[node0 + n], ee = rowptr[node0 + n + 1];
        for (int e = eb; e < ee; ++e) {
            int ls = esrc[e];
            const float4 v = *(const float4*)(Tl + ls * LS + c4);
            acc.x += v.x; acc.y += v.y; acc.z += v.z; acc.w += v.w;
        }
        float w = dl[n];
        float4 b4 = *(const float4*)(bias + c4);
        float4 o;
        o.x = b4.x + w * acc.x; o.y = b4.y + w * acc.y;
        o.z = b4.z + w * acc.z; o.w = b4.w + w * acc.w;
        if (RELU) {
            o.x = fmaxf(o.x, 0.f); o.y = fmaxf(o.y, 0.f);
            o.z = fmaxf(o.z, 0.f); o.w = fmaxf(o.w, 0.f);
        }
        *(float4*)(out + (size_t)(node0 + n) * ldo + c4) = o;
    }
}

// ------------------------------------------------ attention (split-K, tiled SM)
// grid = NGRAPH*4 (graph, head); block = 256 = 128 queries x 2 key-halves.
// Tiles of 8 keys; defer-max rescale (THR=8, p<=e^8 safe in fp32).
// All Ks/Vs reads are lane-uniform per wave (broadcast, conflict-free).
template<int NK, bool QSH>
__global__ __launch_bounds__(256) void k_attn(
    const float* __restrict__ Q, const float* __restrict__ K,
    const float* __restrict__ V, float* __restrict__ O)
{
    constexpr int KH = NK / 2;
    __shared__ float Ks[NK * 16];
    __shared__ float Vs[NK * 16];
    __shared__ float Ml[128 * 18];         // half-1 partials: m, l, acc[16]
    const int g = blockIdx.x >> 2;
    const int h = blockIdx.x & 3;
    const int tid = threadIdx.x;
    for (int i = tid; i < NK * 4; i += 256) {
        int k = i >> 2, dc = (i & 3) << 2;
        const size_t off = ((size_t)g * NK + k) * HDIM + h * 16 + dc;
        *(float4*)(Ks + k * 16 + dc) = *(const float4*)(K + off);
        *(float4*)(Vs + k * 16 + dc) = *(const float4*)(V + off);
    }
    __syncthreads();
    const int q = tid & 127;
    const int half = tid >> 7;
    const int k0 = half * KH;
    const float* qp = QSH ? (Q + (size_t)q * HDIM + h * 16)
                          : (Q + ((size_t)g * K1Q + q) * HDIM + h * 16);
    float qv[16];
#pragma unroll
    for (int d = 0; d < 16; ++d) qv[d] = qp[d];

    float m = -1e30f, l = 0.f;
    float acc[16];
#pragma unroll
    for (int d = 0; d < 16; ++d) acc[d] = 0.f;

    for (int kt = 0; kt < KH; kt += 8) {
        const int kb = k0 + kt;
        float s[8];
#pragma unroll
        for (int j = 0; j < 8; ++j) {
            float t = 0.f;
#pragma unroll
            for (int d4 = 0; d4 < 4; ++d4) {
                float4 kv = *(const float4*)(Ks + (kb + j) * 16 + d4 * 4);
                t += qv[d4*4] * kv.x + qv[d4*4+1] * kv.y
                   + qv[d4*4+2] * kv.z + qv[d4*4+3] * kv.w;
            }
            s[j] = t * 0.125f;
        }
        float tmax = fmaxf(fmaxf(fmaxf(s[0], s[1]), fmaxf(s[2], s[3])),
                           fmaxf(fmaxf(s[4], s[5]), fmaxf(s[6], s[7])));
        if (tmax > m + 8.f) {              // defer-max: rescale only on big jump
            float cr = __expf(m - tmax);
            l *= cr;
#pragma unroll
            for (int d = 0; d < 16; ++d) acc[d] *= cr;
            m = tmax;
        }
        float p[8];
#pragma unroll
        for (int j = 0; j < 8; ++j) { p[j] = __expf(s[j] - m); l += p[j]; }
#pragma unroll
        for (int d4 = 0; d4 < 4; ++d4) {
#pragma unroll
            for (int j = 0; j < 8; ++j) {
                float4 v = *(const float4*)(Vs + (kb + j) * 16 + d4 * 4);
                acc[d4*4]   += p[j] * v.x;
                acc[d4*4+1] += p[j] * v.y;
                acc[d4*4+2] += p[j] * v.z;
                acc[d4*4+3] += p[j] * v.w;
            }
        }
    }
    if (half) {
        float* w = Ml + q * 18;
        w[0] = m; w[1] = l;
#pragma unroll
        for (int d = 0; d < 16; ++d) w[2 + d] = acc[d];
    }
    __syncthreads();
    if (!half) {
        const float* r = Ml + q * 18;
        float m1 = r[0], l1 = r[1];
        float M = fmaxf(m, m1);
        float c0 = __expf(m - M), c1 = __expf(m1 - M);
        float inv = 1.f / (l * c0 + l1 * c1);
        float* op = O + ((size_t)g * K1Q + q) * HDIM + h * 16;
#pragma unroll
        for (int d = 0; d < 16; ++d) op[d] = (acc[d] * c0 + r[2 + d] * c1) * inv;
    }
}

// PMA2: 1 query, 128 keys. block = 256 = 4 graphs x 64 lanes (lane = h*16+d)
__global__ __launch_bounds__(256) void k_attn_pma2(
    const float* __restrict__ Q2p, const float* __restrict__ K3,
    const float* __restrict__ V3, float* __restrict__ O3)
{
    const int t = threadIdx.x;
    const int lane = t & 63;
    const int g = blockIdx.x * 4 + (t >> 6);
    const float q = Q2p[lane];
    const float* Kg = K3 + (size_t)g * 128 * HDIM + lane;
    const float* Vg = V3 + (size_t)g * 128 * HDIM + lane;
    float m = -1e30f, l = 0.f, acc = 0.f;
    for (int k = 0; k < 128; ++k) {
        float s = q * Kg[(size_t)k * HDIM];
        s += __shfl_xor(s, 1); s += __shfl_xor(s, 2);
        s += __shfl_xor(s, 4); s += __shfl_xor(s, 8);
        s *= 0.125f;
        float mn = fmaxf(m, s);
        float cr = __expf(m - mn), p = __expf(s - mn);
        l = l * cr + p;
        acc = acc * cr + p * Vg[(size_t)k * HDIM];
        m = mn;
    }
    O3[(size_t)g * HDIM + lane] = acc / l;
}

// -------------------------------------------- MAB epilogue: o = AO + Q ; out = o + relu(o@W + b)
// NQ = 0: Q per-row; NQ = 1: single shared row; NQ = 128: shared, row & 127
// W read from LDS in-loop (same spill mechanism as k_gemm).
template<int NQ>
__global__ __launch_bounds__(256) void k_mab_epi(
    const float* __restrict__ AO, const float* __restrict__ Qsrc,
    const float* __restrict__ W, const float* __restrict__ bias,
    float* __restrict__ out, int M)
{
    constexpr int TM = 128, KK = 64, CO = 64, WTS = KK + 4;
    __shared__ float Os[TM * KK];
    __shared__ float Wt[CO * WTS];
    const int tid = threadIdx.x;
    const int row0 = blockIdx.x * TM;
    for (int i = tid; i < KK * CO; i += 256) {
        int k = i >> 6, c = i & 63;
        Wt[c * WTS + k] = W[i];
    }
    for (int i = tid; i < TM * 16; i += 256) {
        int r = i >> 4, v = (i & 15) << 2;
        int gr = row0 + r;
        float4 a = make_float4(0.f, 0.f, 0.f, 0.f);
        if (gr < M) {
            float4 x = *(const float4*)(AO + (size_t)gr * KK + v);
            int qr = (NQ == 0) ? gr : (NQ == 1 ? 0 : (gr & (NQ - 1)));
            float4 qv = *(const float4*)(Qsrc + (size_t)qr * KK + v);
            a.x = x.x + qv.x; a.y = x.y + qv.y; a.z = x.z + qv.z; a.w = x.w + qv.w;
        }
        *(float4*)(Os + r * KK + v) = a;
    }
    __syncthreads();
    const int co = tid & 63, g = tid >> 6;
    float acc[32];
#pragma unroll
    for (int r = 0; r < 32; ++r) acc[r] = 0.f;
    const float* wrow = Wt + co * WTS;
    for (int kk = 0; kk < KK / 4; ++kk) {
        float4 w = *(const float4*)(wrow + kk * 4);
#pragma unroll
        for (int r = 0; r < 32; ++r) {
            float4 a = *(const float4*)(Os + (g * 32 + r) * KK + kk * 4);
            acc[r] += a.x * w.x + a.y * w.y + a.z * w.z + a.w * w.w;
        }
    }
    float b = bias[co];
#pragma unroll
    for (int r = 0; r < 32; ++r) {
        int gr = row0 + g * 32 + r;
        if (gr < M) {
            float o = Os[(g * 32 + r) * KK + co];
            out[(size_t)gr * CO + co] = o + fmaxf(acc[r] + b, 0.f);
        }
    }
}

// -------------------------------------------------------- final MLP head
// NOTE: d_out is FLOAT32 (reference output dtype).
__global__ __launch_bounds__(64) void k_head(
    const float* __restrict__ BX3,
    const float* __restrict__ W1, const float* __restrict__ b1,
    const float* __restrict__ W2, const float* __restrict__ b2,
    const float* __restrict__ W3, const float* __restrict__ b3,
    float* __restrict__ outp)
{
    __shared__ float w1[64 * 32], w2[32 * 16], w3[32], bb1[32], bb2[16], bb3[2];
    const int tid = threadIdx.x;
    for (int i = tid; i < 64 * 32; i += 64) w1[i] = W1[i];
    for (int i = tid; i < 32 * 16; i += 64) w2[i] = W2[i];
    if (tid < 32) { w3[tid] = W3[tid]; bb1[tid] = b1[tid]; }
    if (tid < 16) bb2[tid] = b2[tid];
    if (tid < 2)  bb3[tid] = b3[tid];
    __syncthreads();
    const int g = blockIdx.x * 64 + tid;
    float x[64];
#pragma unroll
    for (int v = 0; v < 16; ++v) {
        float4 t = *(const float4*)(BX3 + (size_t)g * 64 + v * 4);
        x[v*4] = t.x; x[v*4+1] = t.y; x[v*4+2] = t.z; x[v*4+3] = t.w;
    }
    float gv[32];
    for (int c = 0; c < 32; ++c) {
        float a = bb1[c];
        for (int k = 0; k < 64; ++k) a += x[k] * w1[k * 32 + c];
        gv[c] = a;
    }
    float h1[16];
    for (int c = 0; c < 16; ++c) {
        float a = bb2[c];
        for (int k = 0; k < 32; ++k) a += gv[k] * w2[k * 16 + c];
        h1[c] = fmaxf(a, 0.f);
    }
    float z0 = bb3[0], z1 = bb3[1];
    for (int k = 0; k < 16; ++k) { z0 += h1[k] * w3[k * 2]; z1 += h1[k] * w3[k * 2 + 1]; }
    float mm = fmaxf(z0, z1);
    float ls = mm + logf(__expf(z0 - mm) + __expf(z1 - mm));
    outp[g * 2]     = z0 - ls;
    outp[g * 2 + 1] = z1 - ls;
}

// =========================================================================
extern "C" void kernel_launch(void* const* d_in, const int* in_sizes, int n_in,
                              void* d_out, int out_size, void* d_ws, size_t ws_size,
                              hipStream_t stream) {
    const float* x0  = (const float*)d_in[0];
    const int*   ei  = (const int*)d_in[1];
    const float* c1W = (const float*)d_in[3];  const float* c1b = (const float*)d_in[4];
    const float* c2W = (const float*)d_in[5];  const float* c2b = (const float*)d_in[6];
    const float* c3W = (const float*)d_in[7];  const float* c3b = (const float*)d_in[8];
    const float* plW = (const float*)d_in[9];  const float* plb = (const float*)d_in[10];
    const float* S1  = (const float*)d_in[11];
    const float* p1Wq = (const float*)d_in[12]; const float* p1bq = (const float*)d_in[13];
    const float* p1Wk = (const float*)d_in[14]; const float* p1bk = (const float*)d_in[15];
    const float* p1Wv = (const float*)d_in[16]; const float* p1bv = (const float*)d_in[17];
    const float* p1Wo = (const float*)d_in[18]; const float* p1bo = (const float*)d_in[19];
    const float* sWq  = (const float*)d_in[20]; const float* sbq  = (const float*)d_in[21];
    const float* sWk  = (const float*)d_in[22]; const float* sbk  = (const float*)d_in[23];
    const float* sWv  = (const float*)d_in[24]; const float* sbv  = (const float*)d_in[25];
    const float* sWo  = (const float*)d_in[26]; const float* sbo  = (const float*)d_in[27];
    const float* p2Wq = (const float*)d_in[28]; const float* p2bq = (const float*)d_in[29];
    const float* p2Wk = (const float*)d_in[30]; const float* p2bk = (const float*)d_in[31];
    const float* p2Wv = (const float*)d_in[32]; const float* p2bv = (const float*)d_in[33];
    const float* p2Wo = (const float*)d_in[34]; const float* p2bo = (const float*)d_in[35];
    const float* S2   = (const float*)d_in[36];
    const float* pl2W = (const float*)d_in[37]; const float* pl2b = (const float*)d_in[38];
    const float* l1W  = (const float*)d_in[39]; const float* l1b  = (const float*)d_in[40];
    const float* l2W  = (const float*)d_in[41]; const float* l2b  = (const float*)d_in[42];

    const int* src = ei;
    const int* dst = ei + NEDGE;

    float* ws = (float*)d_ws;
    float* dinv = ws;                               // [N]
    size_t off = N_NODES;
    int* epack  = (int*)(ws + off); off += NEDGE;   // edges sorted by graph
    int* h      = (int*)(ws + off); off += NBLK * 256;
    int* binTot = (int*)(ws + off); off += 256;
    int* starts = (int*)(ws + off); off += 257;
    int* esrc   = (int*)(ws + off); off += NEDGE;   // CSR src-local, sorted by dst
    int* rowptr = (int*)(ws + off); off += N_NODES + 1;
    off = (off + 255) & ~(size_t)255;
    float* Qp  = ws + off; off += K1Q * HDIM;       // [128,64]
    float* Q2p = ws + off; off += HDIM;
    float* O3  = ws + off; off += NGRAPH * HDIM;
    float* BX3 = ws + off; off += NGRAPH * HDIM;
    off = (off + 1023) & ~(size_t)1023;
    float* P0 = ws + off;
    const size_t SL = (size_t)N_NODES * 32;         // one [N,32] slab
    float* T32 = P0;                // GEMM scratch [N,32]
    float* T64 = P0;                // GEMM scratch [N,64] (P0,P1)
    float* XC  = P0 + 2 * SL;       // [N,96] concat x1|x2|x3 (P2..P4)
    float* XL  = P0 + 5 * SL;       // [N,64] (P5,P6)
    float* KD  = P0 + 2 * SL;       // [N,64] (P2,P3)  - after XC dead
    float* VD  = P0 + 5 * SL;       // [N,64] (P5,P6)  - after XL dead
    float* O1  = P0 + 4 * SL;               // [B,128,64]
    float* BX1 = P0 + 4 * SL + SL / 2;      // [B,128,64]
    float* Qs  = P0;                        // SAB phase reuses P0..P3
    float* Ks_ = P0 + SL / 2;
    float* Vs_ = P0 + SL;
    float* O2  = P0 + SL + SL / 2;
    float* BX2 = P0 + 2 * SL;
    float* K3  = P0 + 2 * SL + SL / 2;
    float* V3  = P0 + 3 * SL;

    // edge sort by graph, then by dst within graph -> CSR; dinv from degrees
    k_hist2<<<NBLK, 256, 0, stream>>>(dst, h);
    k_scan_bins<<<256, 256, 0, stream>>>(h, binTot);
    k_binstart<<<1, 256, 0, stream>>>(binTot, starts);
    k_scatter2<<<NBLK, 256, 0, stream>>>(src, dst, h, starts, epack);
    k_sort_dst<<<NGRAPH, 256, 0, stream>>>(epack, starts, esrc, rowptr);
    k_dinv2<<<512, 256, 0, stream>>>(rowptr, dinv);

    // conv1/2/3 -> XC (stride 96)
    k_gemm<64, 128, 32, 0><<<2048, 256, 0, stream>>>(x0, FIN, c1W, nullptr, T32, 32, N_NODES);
    k_gcn_agg2<1><<<256, 256, 0, stream>>>(T32, 32, dinv, c1b, esrc, rowptr, XC, 96);
    k_gemm<128, 32, 32, 0><<<1024, 256, 0, stream>>>(XC, 96, c2W, nullptr, T32, 32, N_NODES);
    k_gcn_agg2<1><<<256, 256, 0, stream>>>(T32, 32, dinv, c2b, esrc, rowptr, XC + 32, 96);
    k_gemm<128, 32, 32, 0><<<1024, 256, 0, stream>>>(XC + 32, 96, c3W, nullptr, T32, 32, N_NODES);
    k_gcn_agg2<1><<<256, 256, 0, stream>>>(T32, 32, dinv, c3b, esrc, rowptr, XC + 64, 96);

    // xl = concat @ plW + plb
    k_gemm<64, 96, 64, 1><<<2048, 256, 0, stream>>>(XC, 96, plW, plb, XL, 64, N_NODES);

    // K/V GCN convs -> KD, VD
    k_gemm<128, 64, 64, 0><<<1024, 256, 0, stream>>>(XL, 64, p1Wk, nullptr, T64, 64, N_NODES);
    k_gcn_agg2<0><<<256, 256, 0, stream>>>(T64, 64, dinv, p1bk, esrc, rowptr, KD, 64);
    k_gcn_agg2<0><<<256, 256, 0, stream>>>(T64 + 32, 64, dinv, p1bk + 32, esrc, rowptr, KD + 32, 64);
    k_gemm<128, 64, 64, 0><<<1024, 256, 0, stream>>>(XL, 64, p1Wv, nullptr, T64, 64, N_NODES);
    k_gcn_agg2<0><<<256, 256, 0, stream>>>(T64, 64, dinv, p1bv, esrc, rowptr, VD, 64);
    k_gcn_agg2<0><<<256, 256, 0, stream>>>(T64 + 32, 64, dinv, p1bv + 32, esrc, rowptr, VD + 32, 64);

    // MAB1 (PMA with 128 seeds)
    k_gemm<128, 64, 64, 1><<<1, 256, 0, stream>>>(S1, 64, p1Wq, p1bq, Qp, 64, K1Q);
    k_attn<512, true><<<NGRAPH * 4, 256, 0, stream>>>(Qp, KD, VD, O1);
    k_mab_epi<128><<<256, 256, 0, stream>>>(O1, Qp, p1Wo, p1bo, BX1, NGRAPH * K1Q);

    // SAB
    k_gemm<128, 64, 64, 1><<<256, 256, 0, stream>>>(BX1, 64, sWq, sbq, Qs, 64, NGRAPH * K1Q);
    k_gemm<128, 64, 64, 1><<<256, 256, 0, stream>>>(BX1, 64, sWk, sbk, Ks_, 64, NGRAPH * K1Q);
    k_gemm<128, 64, 64, 1><<<256, 256, 0, stream>>>(BX1, 64, sWv, sbv, Vs_, 64, NGRAPH * K1Q);
    k_attn<128, false><<<NGRAPH * 4, 256, 0, stream>>>(Qs, Ks_, Vs_, O2);
    k_mab_epi<0><<<256, 256, 0, stream>>>(O2, Qs, sWo, sbo, BX2, NGRAPH * K1Q);

    // PMA2 (single seed)
    k_gemm<128, 64, 64, 1><<<256, 256, 0, stream>>>(BX2, 64, p2Wk, p2bk, K3, 64, NGRAPH * K1Q);
    k_gemm<128, 64, 64, 1><<<256, 256, 0, stream>>>(BX2, 64, p2Wv, p2bv, V3, 64, NGRAPH * K1Q);
    k_gemm<128, 64, 64, 1><<<1, 256, 0, stream>>>(S2, 64, p2Wq, p2bq, Q2p, 64, 1);
    k_attn_pma2<<<64, 256, 0, stream>>>(Q2p, K3, V3, O3);
    k_mab_epi<1><<<2, 256, 0, stream>>>(O3, Q2p, p2Wo, p2bo, BX3, NGRAPH);

    // head
    k_head<<<4, 64, 0, stream>>>(BX3, pl2W, pl2b, l1W, l1b, l2W, l2b,
                                 (float*)d_out);
}